// Round 9
// baseline (521.575 us; speedup 1.0000x reference)
//
#include <hip/hip_runtime.h>
#include <hip/hip_bf16.h>

typedef __bf16 bf16_t;
typedef unsigned int uint;
typedef __attribute__((ext_vector_type(8))) __bf16 bf16x8;
typedef __attribute__((ext_vector_type(4))) __bf16 bf16x4;
typedef __attribute__((ext_vector_type(4))) float f32x4;
typedef __attribute__((ext_vector_type(16))) float f32x16;

// ---------------- repack fp32 [R][4096] -> packed hi/lo bf16 [R/128][128 kb][128 r][32 c] ----------------
__global__ __launch_bounds__(256) void repack_hl(const float* __restrict__ src,
                                                 uint16_t* __restrict__ dh,
                                                 uint16_t* __restrict__ dl)
{
    const int p  = blockIdx.y;
    const int kb = blockIdx.x;
    const int tid = threadIdx.x;
    const int rr = tid >> 3;
    const int k4 = tid & 7;
    const int slot = k4 >> 1;
    const int so   = (k4 & 1) * 4;
    uint16_t* bh = dh + ((size_t)p * 128 + kb) * 4096;
    uint16_t* bl = dl + ((size_t)p * 128 + kb) * 4096;
    #pragma unroll
    for (int it = 0; it < 4; ++it) {
        const int r = it * 32 + rr;
        const float4 v = *reinterpret_cast<const float4*>(
            &src[((size_t)p * 128 + r) * 4096 + kb * 32 + k4 * 4]);
        float f[4] = {v.x, v.y, v.z, v.w};
        bf16x4 h, l;
        #pragma unroll
        for (int e = 0; e < 4; ++e) {
            bf16_t hb = (bf16_t)f[e];
            h[e] = hb;
            l[e] = (bf16_t)(f[e] - (float)hb);
        }
        const int pos = r * 32 + ((slot ^ ((r >> 1) & 3)) << 3) + so;
        *reinterpret_cast<bf16x4*>(&bh[pos]) = h;
        *reinterpret_cast<bf16x4*>(&bl[pos]) = l;
    }
}

// hi-only 128-row-panel repack (wo)
__global__ __launch_bounds__(256) void repack_h(const float* __restrict__ src,
                                                uint16_t* __restrict__ dh)
{
    const int p  = blockIdx.y;
    const int kb = blockIdx.x;
    const int tid = threadIdx.x;
    const int rr = tid >> 3;
    const int k4 = tid & 7;
    const int slot = k4 >> 1;
    const int so   = (k4 & 1) * 4;
    uint16_t* bh = dh + ((size_t)p * 128 + kb) * 4096;
    #pragma unroll
    for (int it = 0; it < 4; ++it) {
        const int r = it * 32 + rr;
        const float4 v = *reinterpret_cast<const float4*>(
            &src[((size_t)p * 128 + r) * 4096 + kb * 32 + k4 * 4]);
        float f[4] = {v.x, v.y, v.z, v.w};
        bf16x4 h;
        #pragma unroll
        for (int e = 0; e < 4; ++e) h[e] = (bf16_t)f[e];
        const int pos = r * 32 + ((slot ^ ((r >> 1) & 3)) << 3) + so;
        *reinterpret_cast<bf16x4*>(&bh[pos]) = h;
    }
}

// combined wq|wk|wv -> 96-row-panel packed hi: [64 pan][128 kb][96 r][32 c]
__global__ __launch_bounds__(256) void repack_w96(const float* __restrict__ wq,
                                                  const float* __restrict__ wk,
                                                  const float* __restrict__ wv,
                                                  uint16_t* __restrict__ dst)
{
    const int kb  = blockIdx.x;
    const int pan = blockIdx.y;
    const int tid = threadIdx.x;
    const int k4 = tid & 7;
    const int slot = k4 >> 1;
    const int so   = (k4 & 1) * 4;
    uint16_t* bh = dst + ((size_t)pan * 128 + kb) * 3072;
    #pragma unroll
    for (int it = 0; it < 3; ++it) {
        const int r = it * 32 + (tid >> 3);
        const int n = pan * 96 + r;
        const float* srow = (n < 4096) ? (wq + (size_t)n * 4096)
                          : (n < 5120) ? (wk + (size_t)(n - 4096) * 4096)
                                       : (wv + (size_t)(n - 5120) * 4096);
        const float4 v = *reinterpret_cast<const float4*>(srow + kb * 32 + k4 * 4);
        float f[4] = {v.x, v.y, v.z, v.w};
        bf16x4 h;
        #pragma unroll
        for (int e = 0; e < 4; ++e) h[e] = (bf16_t)f[e];
        const int pos = r * 32 + ((slot ^ ((r >> 1) & 3)) << 3) + so;
        *reinterpret_cast<bf16x4*>(&bh[pos]) = h;
    }
}

// ---------------- QKV GEMM: 256x192, 8 waves, BK=32, 3-buf depth-2, 4-phase interleave ----------------
__global__ __launch_bounds__(512) void gemm_qkv5(const uint16_t* __restrict__ xh,
                                                 const uint16_t* __restrict__ xl,
                                                 const uint16_t* __restrict__ wqkv,
                                                 float* __restrict__ xq,
                                                 float* __restrict__ xk,
                                                 float* __restrict__ xv)
{
    __shared__ char lds[3][45056];   // per buf: Ah 16K | Al 16K | Bh 12K

    const int bid = blockIdx.x;
    const int swz = (bid & 7) * 32 + (bid >> 3);
    const int by = swz >> 5;
    const int bx = swz & 31;
    const int tid = threadIdx.x;
    const int w = tid >> 6, lane = tid & 63;
    const int wm = w >> 2, wn = w & 3;
    const int fr = lane & 15, s4 = lane >> 4;

    const int cw = (w < 4) ? 6 : 5;
    const uint16_t* sp[6];
    int dof[6];
    int stridec[6];
    #pragma unroll
    for (int i = 0; i < 6; ++i) {
        const int c = w + 8 * i;
        dof[i] = c * 1024;
        if (i < 4) {
            const uint16_t* base = (c < 16) ? xh : xl;
            const int cc = c & 15;
            sp[i] = base + (size_t)(2 * by + (cc >> 3)) * 524288 + (cc & 7) * 512 + lane * 8;
            stridec[i] = 4096;
        } else {
            const int cb = c - 32;
            sp[i] = wqkv + (size_t)(bx * 2 + (cb >= 6 ? 1 : 0)) * 393216 + (cb % 6) * 512 + lane * 8;
            stridec[i] = 3072;
        }
    }

    f32x4 acc[8][3] = {};

    // prologue: stage tiles 0,1
    #pragma unroll
    for (int i = 0; i < 6; ++i)
        if (i < cw)
            __builtin_amdgcn_global_load_lds(
                (const __attribute__((address_space(1))) void*)(sp[i]),
                (__attribute__((address_space(3))) void*)(&lds[0][0] + dof[i]), 16, 0, 0);
    #pragma unroll
    for (int i = 0; i < 6; ++i)
        if (i < cw)
            __builtin_amdgcn_global_load_lds(
                (const __attribute__((address_space(1))) void*)(sp[i] + stridec[i]),
                (__attribute__((address_space(3))) void*)(&lds[1][0] + dof[i]), 16, 0, 0);
    if (w < 4) asm volatile("s_waitcnt vmcnt(6)" ::: "memory");
    else       asm volatile("s_waitcnt vmcnt(5)" ::: "memory");
    __builtin_amdgcn_s_barrier();
    __builtin_amdgcn_sched_barrier(0);

    int cur = 0;
    for (int t = 0; t < 128; ++t) {
        const char* b = &lds[cur][0];
        int nb = cur + 2; if (nb >= 3) nb -= 3;
        const bool pre = (t + 2 < 128);

        bf16x8 fb[3];
        #pragma unroll
        for (int p = 0; p < 4; ++p) {
            // --- ds_read this phase's fragments ---
            if (p == 0) {
                #pragma unroll
                for (int j = 0; j < 3; ++j) {
                    const int cbp = wn * 48 + j * 16 + fr;
                    const int pan = (cbp >= 96) ? 1 : 0;
                    const int rb = cbp - pan * 96;
                    fb[j] = *reinterpret_cast<const bf16x8*>(b + 32768 + pan * 6144 + rb * 64 + ((s4 ^ ((rb >> 1) & 3)) << 4));
                }
            }
            bf16x8 fh[2], fl[2];
            #pragma unroll
            for (int f = 0; f < 2; ++f) {
                const int rl = p * 32 + f * 16 + fr;
                const int off = wm * 8192 + rl * 64 + ((s4 ^ ((rl >> 1) & 3)) << 4);
                fh[f] = *reinterpret_cast<const bf16x8*>(b + off);
                fl[f] = *reinterpret_cast<const bf16x8*>(b + 16384 + off);
            }
            // --- issue this phase's share of t+2 staging ---
            if (pre) {
                __builtin_amdgcn_global_load_lds(
                    (const __attribute__((address_space(1))) void*)(sp[p] + (size_t)(t + 2) * stridec[p]),
                    (__attribute__((address_space(3))) void*)(&lds[nb][0] + dof[p]), 16, 0, 0);
                if (p + 4 < cw)
                    __builtin_amdgcn_global_load_lds(
                        (const __attribute__((address_space(1))) void*)(sp[p + 4] + (size_t)(t + 2) * stridec[p + 4]),
                        (__attribute__((address_space(3))) void*)(&lds[nb][0] + dof[p + 4]), 16, 0, 0);
            }
            __builtin_amdgcn_s_barrier();
            asm volatile("s_waitcnt lgkmcnt(0)" ::: "memory");
            __builtin_amdgcn_sched_barrier(0);
            __builtin_amdgcn_s_setprio(1);
            #pragma unroll
            for (int f = 0; f < 2; ++f)
                #pragma unroll
                for (int j = 0; j < 3; ++j) {
                    acc[p * 2 + f][j] = __builtin_amdgcn_mfma_f32_16x16x32_bf16(fh[f], fb[j], acc[p * 2 + f][j], 0, 0, 0);
                    acc[p * 2 + f][j] = __builtin_amdgcn_mfma_f32_16x16x32_bf16(fl[f], fb[j], acc[p * 2 + f][j], 0, 0, 0);
                }
            __builtin_amdgcn_s_setprio(0);
            if (p < 3) __builtin_amdgcn_s_barrier();
        }
        // end of K-step: ensure tile t+1 landed (t+2's cw loads stay in flight)
        if (pre) {
            if (w < 4) asm volatile("s_waitcnt vmcnt(6)" ::: "memory");
            else       asm volatile("s_waitcnt vmcnt(5)" ::: "memory");
        } else {
            asm volatile("s_waitcnt vmcnt(0)" ::: "memory");
        }
        __builtin_amdgcn_s_barrier();
        __builtin_amdgcn_sched_barrier(0);
        if (++cur == 3) cur = 0;
    }

    const int r0 = by * 256 + wm * 128 + s4 * 4;
    const int c0 = bx * 192 + wn * 48 + fr;
    #pragma unroll
    for (int ri = 0; ri < 8; ++ri)
        #pragma unroll
        for (int j = 0; j < 3; ++j) {
            const int col = c0 + j * 16;
            #pragma unroll
            for (int rr = 0; rr < 4; ++rr) {
                const int row = r0 + ri * 16 + rr;
                if (col < 4096)      xq[(size_t)row * 4096 + col] = acc[ri][j][rr];
                else if (col < 5120) xk[(size_t)row * 1024 + (col - 4096)] = acc[ri][j][rr];
                else                 xv[(size_t)row * 1024 + (col - 5120)] = acc[ri][j][rr];
            }
        }
}

// ---------------- Output GEMM: 256x128, same 4-phase pipeline ----------------
__global__ __launch_bounds__(512) void gemm_out5(const uint16_t* __restrict__ aoh,
                                                 const uint16_t* __restrict__ aol,
                                                 const uint16_t* __restrict__ woh,
                                                 float* __restrict__ out)
{
    __shared__ char lds[3][40960];   // Ah 16K | Al 16K | Bh 8K

    const int bid = blockIdx.x;
    const int swz = (bid & 7) * 32 + (bid >> 3);
    const int by = swz >> 5;
    const int bx = swz & 31;
    const int tid = threadIdx.x;
    const int w = tid >> 6, lane = tid & 63;
    const int wm = w >> 2, wn = w & 3;
    const int fr = lane & 15, s4 = lane >> 4;

    const uint16_t* sp[5];
    int dof[5];
    #pragma unroll
    for (int i = 0; i < 5; ++i) {
        const int c = w + 8 * i;
        dof[i] = c * 1024;
        if (i < 4) {
            const uint16_t* base = (c < 16) ? aoh : aol;
            const int cc = c & 15;
            sp[i] = base + (size_t)(2 * by + (cc >> 3)) * 524288 + (cc & 7) * 512 + lane * 8;
        } else {
            sp[i] = woh + (size_t)bx * 524288 + (c - 32) * 512 + lane * 8;
        }
    }

    f32x4 acc[8][2] = {};

    #pragma unroll
    for (int i = 0; i < 5; ++i)
        __builtin_amdgcn_global_load_lds(
            (const __attribute__((address_space(1))) void*)(sp[i]),
            (__attribute__((address_space(3))) void*)(&lds[0][0] + dof[i]), 16, 0, 0);
    #pragma unroll
    for (int i = 0; i < 5; ++i)
        __builtin_amdgcn_global_load_lds(
            (const __attribute__((address_space(1))) void*)(sp[i] + 4096),
            (__attribute__((address_space(3))) void*)(&lds[1][0] + dof[i]), 16, 0, 0);
    asm volatile("s_waitcnt vmcnt(5)" ::: "memory");
    __builtin_amdgcn_s_barrier();
    __builtin_amdgcn_sched_barrier(0);

    int cur = 0;
    for (int t = 0; t < 128; ++t) {
        const char* b = &lds[cur][0];
        int nb = cur + 2; if (nb >= 3) nb -= 3;
        const bool pre = (t + 2 < 128);

        bf16x8 fb[2];
        #pragma unroll
        for (int p = 0; p < 4; ++p) {
            if (p == 0) {
                #pragma unroll
                for (int j = 0; j < 2; ++j) {
                    const int cbp = wn * 32 + j * 16 + fr;
                    fb[j] = *reinterpret_cast<const bf16x8*>(b + 32768 + cbp * 64 + ((s4 ^ ((cbp >> 1) & 3)) << 4));
                }
            }
            bf16x8 fh[2], fl[2];
            #pragma unroll
            for (int f = 0; f < 2; ++f) {
                const int rl = p * 32 + f * 16 + fr;
                const int off = wm * 8192 + rl * 64 + ((s4 ^ ((rl >> 1) & 3)) << 4);
                fh[f] = *reinterpret_cast<const bf16x8*>(b + off);
                fl[f] = *reinterpret_cast<const bf16x8*>(b + 16384 + off);
            }
            if (pre) {
                __builtin_amdgcn_global_load_lds(
                    (const __attribute__((address_space(1))) void*)(sp[p] + (size_t)(t + 2) * 4096),
                    (__attribute__((address_space(3))) void*)(&lds[nb][0] + dof[p]), 16, 0, 0);
                if (p == 0)
                    __builtin_amdgcn_global_load_lds(
                        (const __attribute__((address_space(1))) void*)(sp[4] + (size_t)(t + 2) * 4096),
                        (__attribute__((address_space(3))) void*)(&lds[nb][0] + dof[4]), 16, 0, 0);
            }
            __builtin_amdgcn_s_barrier();
            asm volatile("s_waitcnt lgkmcnt(0)" ::: "memory");
            __builtin_amdgcn_sched_barrier(0);
            __builtin_amdgcn_s_setprio(1);
            #pragma unroll
            for (int f = 0; f < 2; ++f)
                #pragma unroll
                for (int j = 0; j < 2; ++j) {
                    acc[p * 2 + f][j] = __builtin_amdgcn_mfma_f32_16x16x32_bf16(fh[f], fb[j], acc[p * 2 + f][j], 0, 0, 0);
                    acc[p * 2 + f][j] = __builtin_amdgcn_mfma_f32_16x16x32_bf16(fl[f], fb[j], acc[p * 2 + f][j], 0, 0, 0);
                }
            __builtin_amdgcn_s_setprio(0);
            if (p < 3) __builtin_amdgcn_s_barrier();
        }
        if (pre) asm volatile("s_waitcnt vmcnt(5)" ::: "memory");
        else     asm volatile("s_waitcnt vmcnt(0)" ::: "memory");
        __builtin_amdgcn_s_barrier();
        __builtin_amdgcn_sched_barrier(0);
        if (++cur == 3) cur = 0;
    }

    const int r0 = by * 256 + wm * 128 + s4 * 4;
    const int c0 = bx * 128 + wn * 32 + fr;
    #pragma unroll
    for (int ri = 0; ri < 8; ++ri)
        #pragma unroll
        for (int j = 0; j < 2; ++j)
            #pragma unroll
            for (int rr = 0; rr < 4; ++rr)
                out[(size_t)(r0 + ri * 16 + rr) * 4096 + c0 + j * 16] = acc[ri][j][rr];
}

// ---------------- RoPE in place; Q additionally scaled by 1/sqrt(128) ----------------
__global__ __launch_bounds__(256) void rope_k(float* __restrict__ xq, float* __restrict__ xk)
{
    const int idx = blockIdx.x * 256 + threadIdx.x;
    const int TOTQ = 2048 * 32 * 64;
    int s, j;
    float* base;
    bool isq = idx < TOTQ;
    if (isq) {
        s = idx >> 11;
        const int rem = idx & 2047;
        j = rem & 63;
        base = xq + (size_t)s * 4096 + (rem >> 6) * 128 + 2 * j;
    } else {
        const int i2 = idx - TOTQ;
        s = i2 >> 9;
        const int rem = i2 & 511;
        j = rem & 63;
        base = xk + (size_t)s * 1024 + (rem >> 6) * 128 + 2 * j;
    }
    const float invf = exp2f(-(float)j * (13.287712379549449f / 64.0f));
    const float ang = (float)s * invf;
    float sn, cs;
    sincosf(ang, &sn, &cs);
    float2 v = *reinterpret_cast<float2*>(base);
    float2 r;
    r.x = v.x * cs - v.y * sn;
    r.y = v.x * sn + v.y * cs;
    if (isq) { r.x *= 0.08838834764831845f; r.y *= 0.08838834764831845f; }
    *reinterpret_cast<float2*>(base) = r;
}

// ---------------- Convert roped K (hi+lo) and raw V (hi only) to blocked+swizzled bf16 tiles ----------------
__global__ __launch_bounds__(256) void conv_kv(const float* __restrict__ xk,
                                               const float* __restrict__ xv,
                                               uint16_t* __restrict__ kvg)
{
    __shared__ float V[32][129];
    const int t = blockIdx.x;
    const int h = blockIdx.y;
    const int tid = threadIdx.x;
    uint16_t* tile = kvg + ((size_t)(h * 64 + t)) * 12288;

    #pragma unroll
    for (int i = 0; i < 4; ++i) {
        int v = i * 256 + tid;
        int row = v >> 5, c4 = (v & 31) * 4;
        *reinterpret_cast<float4*>(&V[row][c4]) =
            *reinterpret_cast<const float4*>(&xv[(size_t)(t * 32 + row) * 1024 + h * 128 + c4]);
    }

    {
        const int r = tid >> 3;
        const int d0 = (tid & 7) * 16;
        float f[16];
        const float* kr = &xk[(size_t)(t * 32 + r) * 1024 + h * 128 + d0];
        *reinterpret_cast<float4*>(&f[0])  = *reinterpret_cast<const float4*>(kr);
        *reinterpret_cast<float4*>(&f[4])  = *reinterpret_cast<const float4*>(kr + 4);
        *reinterpret_cast<float4*>(&f[8])  = *reinterpret_cast<const float4*>(kr + 8);
        *reinterpret_cast<float4*>(&f[12]) = *reinterpret_cast<const float4*>(kr + 12);
        #pragma unroll
        for (int cc = 0; cc < 2; ++cc) {
            bf16x8 hv, lv;
            #pragma unroll
            for (int e = 0; e < 8; ++e) {
                float x = f[cc * 8 + e];
                bf16_t hb = (bf16_t)x;
                hv[e] = hb;
                lv[e] = (bf16_t)(x - (float)hb);
            }
            const int c = (d0 >> 3) + cc;
            const int pos = r * 128 + ((c ^ (r & 15)) << 3);
            *reinterpret_cast<bf16x8*>(&tile[pos]) = hv;
            *reinterpret_cast<bf16x8*>(&tile[4096 + pos]) = lv;
        }
    }
    __syncthreads();
    {
        const int d = tid >> 1;
        const int k0 = (tid & 1) * 16;
        float g[16];
        #pragma unroll
        for (int j = 0; j < 16; ++j) g[j] = V[k0 + j][d];
        #pragma unroll
        for (int cc = 0; cc < 2; ++cc) {
            bf16x8 hv;
            #pragma unroll
            for (int e = 0; e < 8; ++e) hv[e] = (bf16_t)g[cc * 8 + e];
            const int c = (k0 >> 3) + cc;
            const int pos = d * 32 + ((c ^ (d & 3)) << 3);
            *reinterpret_cast<bf16x8*>(&tile[8192 + pos]) = hv;
        }
    }
}

// ---------------- MFMA flash attention (unchanged from round 7/8) ----------------
__device__ __forceinline__ uint cvtpk(float lo, float hi) {
    uint r;
    asm("v_cvt_pk_bf16_f32 %0, %1, %2" : "=v"(r) : "v"(lo), "v"(hi));
    return r;
}
__device__ __forceinline__ void permswap(uint& a, uint& b) {
    asm("v_permlane32_swap_b32 %0, %1" : "+v"(a), "+v"(b));
}
__device__ __forceinline__ bf16x8 pack4(uint w0, uint w1, uint w2, uint w3) {
    union { uint u[4]; bf16x8 v; } t;
    t.u[0] = w0; t.u[1] = w1; t.u[2] = w2; t.u[3] = w3;
    return t.v;
}

__global__ __launch_bounds__(512, 2) void attn_mfma(const float* __restrict__ xq,
                                                    const uint16_t* __restrict__ kvg,
                                                    uint16_t* __restrict__ aoh,
                                                    uint16_t* __restrict__ aol)
{
    __shared__ char lds[2][24576];

    const int b = blockIdx.x;
    const int kvh = b & 7;
    const int r = b >> 3;
    const int h = kvh * 4 + (r & 3);
    const int q0 = (r >> 2) * 256;
    const int tid = threadIdx.x;
    const int w = tid >> 6;
    const int lane = tid & 63;
    const int ln31 = lane & 31;
    const int hi = lane >> 5;

    const int q = q0 + w * 32 + ln31;
    const float* qrow = xq + (size_t)q * 4096 + h * 128;
    bf16x8 Qh[8];
    #pragma unroll
    for (int ks = 0; ks < 8; ++ks) {
        float f[8];
        *reinterpret_cast<float4*>(&f[0]) = *reinterpret_cast<const float4*>(qrow + ks * 16 + hi * 8);
        *reinterpret_cast<float4*>(&f[4]) = *reinterpret_cast<const float4*>(qrow + ks * 16 + hi * 8 + 4);
        #pragma unroll
        for (int e = 0; e < 8; ++e) Qh[ks][e] = (bf16_t)f[e];
    }

    const char* gkv = (const char*)kvg + (size_t)kvh * 64 * 24576;

    f32x16 oacc[4] = {{}, {}, {}, {}};
    float m = -3.0e38f, l = 0.f;

    {
        #pragma unroll
        for (int i = 0; i < 3; ++i) {
            const int chunk = i * 8 + w;
            __builtin_amdgcn_global_load_lds(
                (const __attribute__((address_space(1))) void*)(gkv + chunk * 1024 + lane * 16),
                (__attribute__((address_space(3))) void*)(&lds[0][chunk * 1024]),
                16, 0, 0);
        }
    }

    for (int t = 0; t < 64; ++t) {
        __syncthreads();
        if (t + 1 < 64) {
            const char* g = gkv + (size_t)(t + 1) * 24576;
            const int buf = (t + 1) & 1;
            #pragma unroll
            for (int i = 0; i < 3; ++i) {
                const int chunk = i * 8 + w;
                __builtin_amdgcn_global_load_lds(
                    (const __attribute__((address_space(1))) void*)(g + chunk * 1024 + lane * 16),
                    (__attribute__((address_space(3))) void*)(&lds[buf][chunk * 1024]),
                    16, 0, 0);
            }
        }
        const int cur = t & 1;
        const char* Kh = lds[cur];
        const char* Kl = lds[cur] + 8192;
        const char* Vh = lds[cur] + 16384;

        f32x16 s = {};
        __builtin_amdgcn_s_setprio(1);
        #pragma unroll
        for (int ks = 0; ks < 8; ++ks) {
            const int byt = ln31 * 256 + ((ks * 32 + hi * 16) ^ ((ln31 & 15) << 4));
            bf16x8 ah = *reinterpret_cast<const bf16x8*>(Kh + byt);
            bf16x8 al = *reinterpret_cast<const bf16x8*>(Kl + byt);
            s = __builtin_amdgcn_mfma_f32_32x32x16_bf16(ah, Qh[ks], s, 0, 0, 0);
            s = __builtin_amdgcn_mfma_f32_32x32x16_bf16(al, Qh[ks], s, 0, 0, 0);
        }
        __builtin_amdgcn_s_setprio(0);

        float pmax = s[0];
        #pragma unroll
        for (int jj = 1; jj < 16; ++jj) pmax = fmaxf(pmax, s[jj]);
        pmax = fmaxf(pmax, __shfl_xor(pmax, 32));
        if (!__all(pmax - m <= 8.0f)) {
            const float mnew = fmaxf(m, pmax);
            const float corr = __expf(m - mnew);
            l *= corr;
            #pragma unroll
            for (int dt = 0; dt < 4; ++dt) oacc[dt] *= corr;
            m = mnew;
        }
        float psum = 0.f;
        #pragma unroll
        for (int jj = 0; jj < 16; ++jj) {
            float pv = __expf(s[jj] - m);
            s[jj] = pv;
            psum += pv;
        }
        psum += __shfl_xor(psum, 32);
        l += psum;

        #pragma unroll
        for (int ks = 0; ks < 2; ++ks) {
            const int b0 = ks * 8;
            uint wa = cvtpk(s[b0 + 0], s[b0 + 1]);
            uint wb = cvtpk(s[b0 + 2], s[b0 + 3]);
            uint wc = cvtpk(s[b0 + 4], s[b0 + 5]);
            uint wd = cvtpk(s[b0 + 6], s[b0 + 7]);
            permswap(wa, wc); permswap(wb, wd);
            bf16x8 Pf = pack4(wa, wb, wc, wd);
            __builtin_amdgcn_s_setprio(1);
            #pragma unroll
            for (int dt = 0; dt < 4; ++dt) {
                const int row = dt * 32 + ln31;
                const int byt = row * 64 + ((ks * 32 + hi * 16) ^ ((row & 3) << 4));
                bf16x8 vh = *reinterpret_cast<const bf16x8*>(Vh + byt);
                oacc[dt] = __builtin_amdgcn_mfma_f32_32x32x16_bf16(vh, Pf, oacc[dt], 0, 0, 0);
            }
            __builtin_amdgcn_s_setprio(0);
        }
    }

    const float invl = 1.0f / l;
    const int p   = q >> 7;
    const int rr_ = q & 127;
    const int rsw = (rr_ >> 1) & 3;
    #pragma unroll
    for (int dt = 0; dt < 4; ++dt) {
        const int kb = h * 4 + dt;
        uint16_t* bh = aoh + ((size_t)p * 128 + kb) * 4096;
        uint16_t* bl = aol + ((size_t)p * 128 + kb) * 4096;
        #pragma unroll
        for (int g4 = 0; g4 < 4; ++g4) {
            bf16x4 hv, lv;
            #pragma unroll
            for (int e = 0; e < 4; ++e) {
                float v = oacc[dt][g4 * 4 + e] * invl;
                bf16_t hb = (bf16_t)v;
                hv[e] = hb;
                lv[e] = (bf16_t)(v - (float)hb);
            }
            const int pos = rr_ * 32 + ((g4 ^ rsw) << 3) + 4 * hi;
            *reinterpret_cast<bf16x4*>(&bh[pos]) = hv;
            *reinterpret_cast<bf16x4*>(&bl[pos]) = lv;
        }
    }
}

extern "C" void kernel_launch(void* const* d_in, const int* in_sizes, int n_in,
                              void* d_out, int out_size, void* d_ws, size_t ws_size,
                              hipStream_t stream)
{
    const float* x  = (const float*)d_in[0];
    const float* wq = (const float*)d_in[1];
    const float* wk = (const float*)d_in[2];
    const float* wv = (const float*)d_in[3];
    const float* wo = (const float*)d_in[4];
    float* out = (float*)d_out;

    float* ws = (float*)d_ws;
    float*    xq   = ws;                           // [0, 8388608)
    uint16_t* kvg  = (uint16_t*)(ws + 8388608);    // [8388608, 11534336)
    float*    xk   = ws + 12582912;
    float*    xv   = ws + 14680064;
    uint16_t* aoh  = (uint16_t*)(ws + 12582912);   // reuses xk slot after conv_kv
    uint16_t* aol  = (uint16_t*)(ws + 16777216);
    uint16_t* xh   = (uint16_t*)(ws + 20971520);
    uint16_t* xl   = (uint16_t*)(ws + 25165824);
    uint16_t* wqkv = (uint16_t*)(ws + 29360128);
    uint16_t* woh  = (uint16_t*)(ws + 41943040);

    dim3 blk(256);
    repack_hl <<<dim3(128, 16), blk, 0, stream>>>(x, xh, xl);
    repack_w96<<<dim3(128, 64), blk, 0, stream>>>(wq, wk, wv, wqkv);
    gemm_qkv5 <<<dim3(256), dim3(512), 0, stream>>>(xh, xl, wqkv, xq, xk, xv);
    repack_h  <<<dim3(128, 32), blk, 0, stream>>>(wo, woh);
    rope_k    <<<dim3(20480), blk, 0, stream>>>(xq, xk);
    conv_kv   <<<dim3(64, 8), blk, 0, stream>>>(xk, xv, kvg);
    attn_mfma <<<dim3(256), dim3(512), 0, stream>>>(xq, kvg, aoh, aol);
    gemm_out5 <<<dim3(256), dim3(512), 0, stream>>>(aoh, aol, woh, out);
}

// Round 10
// 460.813 us; speedup vs baseline: 1.1319x; 1.1319x over previous
//
#include <hip/hip_runtime.h>
#include <hip/hip_bf16.h>

typedef __bf16 bf16_t;
typedef unsigned int uint;
typedef __attribute__((ext_vector_type(8))) __bf16 bf16x8;
typedef __attribute__((ext_vector_type(4))) __bf16 bf16x4;
typedef __attribute__((ext_vector_type(4))) float f32x4;
typedef __attribute__((ext_vector_type(16))) float f32x16;

// ---------------- repack fp32 [R][4096] -> packed hi/lo bf16 [R/128][128 kb][128 r][32 c] ----------------
__global__ __launch_bounds__(256) void repack_hl(const float* __restrict__ src,
                                                 uint16_t* __restrict__ dh,
                                                 uint16_t* __restrict__ dl)
{
    const int p  = blockIdx.y;
    const int kb = blockIdx.x;
    const int tid = threadIdx.x;
    const int rr = tid >> 3;
    const int k4 = tid & 7;
    const int slot = k4 >> 1;
    const int so   = (k4 & 1) * 4;
    uint16_t* bh = dh + ((size_t)p * 128 + kb) * 4096;
    uint16_t* bl = dl + ((size_t)p * 128 + kb) * 4096;
    #pragma unroll
    for (int it = 0; it < 4; ++it) {
        const int r = it * 32 + rr;
        const float4 v = *reinterpret_cast<const float4*>(
            &src[((size_t)p * 128 + r) * 4096 + kb * 32 + k4 * 4]);
        float f[4] = {v.x, v.y, v.z, v.w};
        bf16x4 h, l;
        #pragma unroll
        for (int e = 0; e < 4; ++e) {
            bf16_t hb = (bf16_t)f[e];
            h[e] = hb;
            l[e] = (bf16_t)(f[e] - (float)hb);
        }
        const int pos = r * 32 + ((slot ^ ((r >> 1) & 3)) << 3) + so;
        *reinterpret_cast<bf16x4*>(&bh[pos]) = h;
        *reinterpret_cast<bf16x4*>(&bl[pos]) = l;
    }
}

// hi-only 128-row-panel repack (wo)
__global__ __launch_bounds__(256) void repack_h(const float* __restrict__ src,
                                                uint16_t* __restrict__ dh)
{
    const int p  = blockIdx.y;
    const int kb = blockIdx.x;
    const int tid = threadIdx.x;
    const int rr = tid >> 3;
    const int k4 = tid & 7;
    const int slot = k4 >> 1;
    const int so   = (k4 & 1) * 4;
    uint16_t* bh = dh + ((size_t)p * 128 + kb) * 4096;
    #pragma unroll
    for (int it = 0; it < 4; ++it) {
        const int r = it * 32 + rr;
        const float4 v = *reinterpret_cast<const float4*>(
            &src[((size_t)p * 128 + r) * 4096 + kb * 32 + k4 * 4]);
        float f[4] = {v.x, v.y, v.z, v.w};
        bf16x4 h;
        #pragma unroll
        for (int e = 0; e < 4; ++e) h[e] = (bf16_t)f[e];
        const int pos = r * 32 + ((slot ^ ((r >> 1) & 3)) << 3) + so;
        *reinterpret_cast<bf16x4*>(&bh[pos]) = h;
    }
}

// combined wq|wk|wv -> 96-row-panel packed hi: [64 pan][128 kb][96 r][32 c]
__global__ __launch_bounds__(256) void repack_w96(const float* __restrict__ wq,
                                                  const float* __restrict__ wk,
                                                  const float* __restrict__ wv,
                                                  uint16_t* __restrict__ dst)
{
    const int kb  = blockIdx.x;
    const int pan = blockIdx.y;
    const int tid = threadIdx.x;
    const int k4 = tid & 7;
    const int slot = k4 >> 1;
    const int so   = (k4 & 1) * 4;
    uint16_t* bh = dst + ((size_t)pan * 128 + kb) * 3072;
    #pragma unroll
    for (int it = 0; it < 3; ++it) {
        const int r = it * 32 + (tid >> 3);
        const int n = pan * 96 + r;
        const float* srow = (n < 4096) ? (wq + (size_t)n * 4096)
                          : (n < 5120) ? (wk + (size_t)(n - 4096) * 4096)
                                       : (wv + (size_t)(n - 5120) * 4096);
        const float4 v = *reinterpret_cast<const float4*>(srow + kb * 32 + k4 * 4);
        float f[4] = {v.x, v.y, v.z, v.w};
        bf16x4 h;
        #pragma unroll
        for (int e = 0; e < 4; ++e) h[e] = (bf16_t)f[e];
        const int pos = r * 32 + ((slot ^ ((r >> 1) & 3)) << 3) + so;
        *reinterpret_cast<bf16x4*>(&bh[pos]) = h;
    }
}

// ---------------- QKV GEMM: 256x192, 8 waves, BK=32, 3-buf depth-2, counted vmcnt (round-8 proven) ----------------
__global__ __launch_bounds__(512) void gemm_qkv4(const uint16_t* __restrict__ xh,
                                                 const uint16_t* __restrict__ xl,
                                                 const uint16_t* __restrict__ wqkv,
                                                 float* __restrict__ xq,
                                                 float* __restrict__ xk,
                                                 float* __restrict__ xv)
{
    __shared__ char lds[3][45056];   // per buf: Ah 16K | Al 16K | Bh 12K

    const int bid = blockIdx.x;
    const int swz = (bid & 7) * 32 + (bid >> 3);
    const int by = swz >> 5;
    const int bx = swz & 31;
    const int tid = threadIdx.x;
    const int w = tid >> 6, lane = tid & 63;
    const int wm = w >> 2, wn = w & 3;
    const int fr = lane & 15, s4 = lane >> 4;

    const int cw = (w < 4) ? 6 : 5;
    const uint16_t* sp[6];
    int dof[6];
    int stridec[6];
    #pragma unroll
    for (int i = 0; i < 6; ++i) {
        const int c = w + 8 * i;
        dof[i] = c * 1024;
        if (i < 4) {
            const uint16_t* base = (c < 16) ? xh : xl;
            const int cc = c & 15;
            sp[i] = base + (size_t)(2 * by + (cc >> 3)) * 524288 + (cc & 7) * 512 + lane * 8;
            stridec[i] = 4096;
        } else {
            const int cb = c - 32;
            sp[i] = wqkv + (size_t)(bx * 2 + (cb >= 6 ? 1 : 0)) * 393216 + (cb % 6) * 512 + lane * 8;
            stridec[i] = 3072;
        }
    }

    f32x4 acc[8][3] = {};

    #pragma unroll
    for (int i = 0; i < 6; ++i)
        if (i < cw)
            __builtin_amdgcn_global_load_lds(
                (const __attribute__((address_space(1))) void*)(sp[i]),
                (__attribute__((address_space(3))) void*)(&lds[0][0] + dof[i]), 16, 0, 0);
    #pragma unroll
    for (int i = 0; i < 6; ++i)
        if (i < cw)
            __builtin_amdgcn_global_load_lds(
                (const __attribute__((address_space(1))) void*)(sp[i] + stridec[i]),
                (__attribute__((address_space(3))) void*)(&lds[1][0] + dof[i]), 16, 0, 0);
    if (w < 4) asm volatile("s_waitcnt vmcnt(6)" ::: "memory");
    else       asm volatile("s_waitcnt vmcnt(5)" ::: "memory");
    __builtin_amdgcn_s_barrier();
    __builtin_amdgcn_sched_barrier(0);

    int cur = 0;
    for (int t = 0; t < 128; ++t) {
        if (t + 2 < 128) {
            int nb = cur + 2; if (nb >= 3) nb -= 3;
            #pragma unroll
            for (int i = 0; i < 6; ++i)
                if (i < cw)
                    __builtin_amdgcn_global_load_lds(
                        (const __attribute__((address_space(1))) void*)(sp[i] + (size_t)(t + 2) * stridec[i]),
                        (__attribute__((address_space(3))) void*)(&lds[nb][0] + dof[i]), 16, 0, 0);
        }
        const char* b = &lds[cur][0];

        bf16x8 fb[3];
        #pragma unroll
        for (int j = 0; j < 3; ++j) {
            const int cbp = wn * 48 + j * 16 + fr;
            const int pan = (cbp >= 96) ? 1 : 0;
            const int rb = cbp - pan * 96;
            fb[j] = *reinterpret_cast<const bf16x8*>(b + 32768 + pan * 6144 + rb * 64 + ((s4 ^ ((rb >> 1) & 3)) << 4));
        }
        #pragma unroll
        for (int p = 0; p < 4; ++p) {
            bf16x8 fh[2], fl[2];
            #pragma unroll
            for (int f = 0; f < 2; ++f) {
                const int rl = p * 32 + f * 16 + fr;
                const int off = wm * 8192 + rl * 64 + ((s4 ^ ((rl >> 1) & 3)) << 4);
                fh[f] = *reinterpret_cast<const bf16x8*>(b + off);
                fl[f] = *reinterpret_cast<const bf16x8*>(b + 16384 + off);
            }
            __builtin_amdgcn_s_setprio(1);
            #pragma unroll
            for (int f = 0; f < 2; ++f)
                #pragma unroll
                for (int j = 0; j < 3; ++j) {
                    acc[p * 2 + f][j] = __builtin_amdgcn_mfma_f32_16x16x32_bf16(fh[f], fb[j], acc[p * 2 + f][j], 0, 0, 0);
                    acc[p * 2 + f][j] = __builtin_amdgcn_mfma_f32_16x16x32_bf16(fl[f], fb[j], acc[p * 2 + f][j], 0, 0, 0);
                }
            __builtin_amdgcn_s_setprio(0);
        }
        if (t + 2 < 128) {
            if (w < 4) asm volatile("s_waitcnt vmcnt(6)" ::: "memory");
            else       asm volatile("s_waitcnt vmcnt(5)" ::: "memory");
        } else {
            asm volatile("s_waitcnt vmcnt(0)" ::: "memory");
        }
        __builtin_amdgcn_s_barrier();
        __builtin_amdgcn_sched_barrier(0);
        if (++cur == 3) cur = 0;
    }

    const int r0 = by * 256 + wm * 128 + s4 * 4;
    const int c0 = bx * 192 + wn * 48 + fr;
    #pragma unroll
    for (int ri = 0; ri < 8; ++ri)
        #pragma unroll
        for (int j = 0; j < 3; ++j) {
            const int col = c0 + j * 16;
            #pragma unroll
            for (int rr = 0; rr < 4; ++rr) {
                const int row = r0 + ri * 16 + rr;
                if (col < 4096)      xq[(size_t)row * 4096 + col] = acc[ri][j][rr];
                else if (col < 5120) xk[(size_t)row * 1024 + (col - 4096)] = acc[ri][j][rr];
                else                 xv[(size_t)row * 1024 + (col - 5120)] = acc[ri][j][rr];
            }
        }
}

// ---------------- Output GEMM: 256x128, 1-pass (AhBh only), 3-buf depth-2, counted vmcnt ----------------
__global__ __launch_bounds__(512) void gemm_out6(const uint16_t* __restrict__ aoh,
                                                 const uint16_t* __restrict__ woh,
                                                 float* __restrict__ out)
{
    __shared__ char lds[3][24576];   // per buf: Ah 16K | Bh 8K

    const int bid = blockIdx.x;
    const int swz = (bid & 7) * 32 + (bid >> 3);
    const int by = swz >> 5;
    const int bx = swz & 31;
    const int tid = threadIdx.x;
    const int w = tid >> 6, lane = tid & 63;
    const int wm = w >> 2, wn = w & 3;
    const int fr = lane & 15, s4 = lane >> 4;

    const uint16_t* sp[3];
    int dof[3];
    #pragma unroll
    for (int i = 0; i < 3; ++i) {
        const int c = w + 8 * i;       // 0..23
        if (c < 16) {
            sp[i]  = aoh + (size_t)(2 * by + (c >> 3)) * 524288 + (c & 7) * 512 + lane * 8;
            dof[i] = c * 1024;
        } else {
            sp[i]  = woh + (size_t)bx * 524288 + (c - 16) * 512 + lane * 8;
            dof[i] = 16384 + (c - 16) * 1024;
        }
    }

    f32x4 acc[8][2] = {};

    #pragma unroll
    for (int i = 0; i < 3; ++i)
        __builtin_amdgcn_global_load_lds(
            (const __attribute__((address_space(1))) void*)(sp[i]),
            (__attribute__((address_space(3))) void*)(&lds[0][0] + dof[i]), 16, 0, 0);
    #pragma unroll
    for (int i = 0; i < 3; ++i)
        __builtin_amdgcn_global_load_lds(
            (const __attribute__((address_space(1))) void*)(sp[i] + 4096),
            (__attribute__((address_space(3))) void*)(&lds[1][0] + dof[i]), 16, 0, 0);
    asm volatile("s_waitcnt vmcnt(3)" ::: "memory");
    __builtin_amdgcn_s_barrier();
    __builtin_amdgcn_sched_barrier(0);

    int cur = 0;
    for (int t = 0; t < 128; ++t) {
        if (t + 2 < 128) {
            int nb = cur + 2; if (nb >= 3) nb -= 3;
            #pragma unroll
            for (int i = 0; i < 3; ++i)
                __builtin_amdgcn_global_load_lds(
                    (const __attribute__((address_space(1))) void*)(sp[i] + (size_t)(t + 2) * 4096),
                    (__attribute__((address_space(3))) void*)(&lds[nb][0] + dof[i]), 16, 0, 0);
        }
        const char* b = &lds[cur][0];

        bf16x8 fb[2];
        #pragma unroll
        for (int j = 0; j < 2; ++j) {
            const int cbp = wn * 32 + j * 16 + fr;
            fb[j] = *reinterpret_cast<const bf16x8*>(b + 16384 + cbp * 64 + ((s4 ^ ((cbp >> 1) & 3)) << 4));
        }
        #pragma unroll
        for (int p = 0; p < 4; ++p) {
            bf16x8 fh[2];
            #pragma unroll
            for (int f = 0; f < 2; ++f) {
                const int rl = p * 32 + f * 16 + fr;
                fh[f] = *reinterpret_cast<const bf16x8*>(b + wm * 8192 + rl * 64 + ((s4 ^ ((rl >> 1) & 3)) << 4));
            }
            __builtin_amdgcn_s_setprio(1);
            #pragma unroll
            for (int f = 0; f < 2; ++f)
                #pragma unroll
                for (int j = 0; j < 2; ++j)
                    acc[p * 2 + f][j] = __builtin_amdgcn_mfma_f32_16x16x32_bf16(fh[f], fb[j], acc[p * 2 + f][j], 0, 0, 0);
            __builtin_amdgcn_s_setprio(0);
        }
        if (t + 2 < 128) asm volatile("s_waitcnt vmcnt(3)" ::: "memory");
        else             asm volatile("s_waitcnt vmcnt(0)" ::: "memory");
        __builtin_amdgcn_s_barrier();
        __builtin_amdgcn_sched_barrier(0);
        if (++cur == 3) cur = 0;
    }

    const int r0 = by * 256 + wm * 128 + s4 * 4;
    const int c0 = bx * 128 + wn * 32 + fr;
    #pragma unroll
    for (int ri = 0; ri < 8; ++ri)
        #pragma unroll
        for (int j = 0; j < 2; ++j)
            #pragma unroll
            for (int rr = 0; rr < 4; ++rr)
                out[(size_t)(r0 + ri * 16 + rr) * 4096 + c0 + j * 16] = acc[ri][j][rr];
}

// ---------------- RoPE in place; Q additionally scaled by 1/sqrt(128) ----------------
__global__ __launch_bounds__(256) void rope_k(float* __restrict__ xq, float* __restrict__ xk)
{
    const int idx = blockIdx.x * 256 + threadIdx.x;
    const int TOTQ = 2048 * 32 * 64;
    int s, j;
    float* base;
    bool isq = idx < TOTQ;
    if (isq) {
        s = idx >> 11;
        const int rem = idx & 2047;
        j = rem & 63;
        base = xq + (size_t)s * 4096 + (rem >> 6) * 128 + 2 * j;
    } else {
        const int i2 = idx - TOTQ;
        s = i2 >> 9;
        const int rem = i2 & 511;
        j = rem & 63;
        base = xk + (size_t)s * 1024 + (rem >> 6) * 128 + 2 * j;
    }
    const float invf = exp2f(-(float)j * (13.287712379549449f / 64.0f));
    const float ang = (float)s * invf;
    float sn, cs;
    sincosf(ang, &sn, &cs);
    float2 v = *reinterpret_cast<float2*>(base);
    float2 r;
    r.x = v.x * cs - v.y * sn;
    r.y = v.x * sn + v.y * cs;
    if (isq) { r.x *= 0.08838834764831845f; r.y *= 0.08838834764831845f; }
    *reinterpret_cast<float2*>(base) = r;
}

// ---------------- Convert roped K (hi+lo) and raw V (hi only) to blocked+swizzled bf16 tiles ----------------
__global__ __launch_bounds__(256) void conv_kv(const float* __restrict__ xk,
                                               const float* __restrict__ xv,
                                               uint16_t* __restrict__ kvg)
{
    __shared__ float V[32][129];
    const int t = blockIdx.x;
    const int h = blockIdx.y;
    const int tid = threadIdx.x;
    uint16_t* tile = kvg + ((size_t)(h * 64 + t)) * 12288;

    #pragma unroll
    for (int i = 0; i < 4; ++i) {
        int v = i * 256 + tid;
        int row = v >> 5, c4 = (v & 31) * 4;
        *reinterpret_cast<float4*>(&V[row][c4]) =
            *reinterpret_cast<const float4*>(&xv[(size_t)(t * 32 + row) * 1024 + h * 128 + c4]);
    }

    {
        const int r = tid >> 3;
        const int d0 = (tid & 7) * 16;
        float f[16];
        const float* kr = &xk[(size_t)(t * 32 + r) * 1024 + h * 128 + d0];
        *reinterpret_cast<float4*>(&f[0])  = *reinterpret_cast<const float4*>(kr);
        *reinterpret_cast<float4*>(&f[4])  = *reinterpret_cast<const float4*>(kr + 4);
        *reinterpret_cast<float4*>(&f[8])  = *reinterpret_cast<const float4*>(kr + 8);
        *reinterpret_cast<float4*>(&f[12]) = *reinterpret_cast<const float4*>(kr + 12);
        #pragma unroll
        for (int cc = 0; cc < 2; ++cc) {
            bf16x8 hv, lv;
            #pragma unroll
            for (int e = 0; e < 8; ++e) {
                float x = f[cc * 8 + e];
                bf16_t hb = (bf16_t)x;
                hv[e] = hb;
                lv[e] = (bf16_t)(x - (float)hb);
            }
            const int c = (d0 >> 3) + cc;
            const int pos = r * 128 + ((c ^ (r & 15)) << 3);
            *reinterpret_cast<bf16x8*>(&tile[pos]) = hv;
            *reinterpret_cast<bf16x8*>(&tile[4096 + pos]) = lv;
        }
    }
    __syncthreads();
    {
        const int d = tid >> 1;
        const int k0 = (tid & 1) * 16;
        float g[16];
        #pragma unroll
        for (int j = 0; j < 16; ++j) g[j] = V[k0 + j][d];
        #pragma unroll
        for (int cc = 0; cc < 2; ++cc) {
            bf16x8 hv;
            #pragma unroll
            for (int e = 0; e < 8; ++e) hv[e] = (bf16_t)g[cc * 8 + e];
            const int c = (k0 >> 3) + cc;
            const int pos = d * 32 + ((c ^ (d & 3)) << 3);
            *reinterpret_cast<bf16x8*>(&tile[8192 + pos]) = hv;
        }
    }
}

// ---------------- MFMA flash attention (split QK chains, 1-pass PV, defer-max, hi-only epilogue) ----------------
__device__ __forceinline__ uint cvtpk(float lo, float hi) {
    uint r;
    asm("v_cvt_pk_bf16_f32 %0, %1, %2" : "=v"(r) : "v"(lo), "v"(hi));
    return r;
}
__device__ __forceinline__ void permswap(uint& a, uint& b) {
    asm("v_permlane32_swap_b32 %0, %1" : "+v"(a), "+v"(b));
}
__device__ __forceinline__ bf16x8 pack4(uint w0, uint w1, uint w2, uint w3) {
    union { uint u[4]; bf16x8 v; } t;
    t.u[0] = w0; t.u[1] = w1; t.u[2] = w2; t.u[3] = w3;
    return t.v;
}

__global__ __launch_bounds__(512, 2) void attn_mfma(const float* __restrict__ xq,
                                                    const uint16_t* __restrict__ kvg,
                                                    uint16_t* __restrict__ aoh)
{
    __shared__ char lds[2][24576];

    const int b = blockIdx.x;
    const int kvh = b & 7;
    const int r = b >> 3;
    const int h = kvh * 4 + (r & 3);
    const int q0 = (r >> 2) * 256;
    const int tid = threadIdx.x;
    const int w = tid >> 6;
    const int lane = tid & 63;
    const int ln31 = lane & 31;
    const int hi = lane >> 5;

    const int q = q0 + w * 32 + ln31;
    const float* qrow = xq + (size_t)q * 4096 + h * 128;
    bf16x8 Qh[8];
    #pragma unroll
    for (int ks = 0; ks < 8; ++ks) {
        float f[8];
        *reinterpret_cast<float4*>(&f[0]) = *reinterpret_cast<const float4*>(qrow + ks * 16 + hi * 8);
        *reinterpret_cast<float4*>(&f[4]) = *reinterpret_cast<const float4*>(qrow + ks * 16 + hi * 8 + 4);
        #pragma unroll
        for (int e = 0; e < 8; ++e) Qh[ks][e] = (bf16_t)f[e];
    }

    const char* gkv = (const char*)kvg + (size_t)kvh * 64 * 24576;

    f32x16 oacc[4] = {{}, {}, {}, {}};
    float m = -3.0e38f, l = 0.f;

    {
        #pragma unroll
        for (int i = 0; i < 3; ++i) {
            const int chunk = i * 8 + w;
            __builtin_amdgcn_global_load_lds(
                (const __attribute__((address_space(1))) void*)(gkv + chunk * 1024 + lane * 16),
                (__attribute__((address_space(3))) void*)(&lds[0][chunk * 1024]),
                16, 0, 0);
        }
    }

    for (int t = 0; t < 64; ++t) {
        __syncthreads();
        if (t + 1 < 64) {
            const char* g = gkv + (size_t)(t + 1) * 24576;
            const int buf = (t + 1) & 1;
            #pragma unroll
            for (int i = 0; i < 3; ++i) {
                const int chunk = i * 8 + w;
                __builtin_amdgcn_global_load_lds(
                    (const __attribute__((address_space(1))) void*)(g + chunk * 1024 + lane * 16),
                    (__attribute__((address_space(3))) void*)(&lds[buf][chunk * 1024]),
                    16, 0, 0);
            }
        }
        const int cur = t & 1;
        const char* Kh = lds[cur];
        const char* Kl = lds[cur] + 8192;
        const char* Vh = lds[cur] + 16384;

        // ---- swapped QK^T: two independent 8-deep accumulation chains ----
        f32x16 s0 = {}, s1 = {};
        __builtin_amdgcn_s_setprio(1);
        #pragma unroll
        for (int ks = 0; ks < 8; ++ks) {
            const int byt = ln31 * 256 + ((ks * 32 + hi * 16) ^ ((ln31 & 15) << 4));
            bf16x8 ah = *reinterpret_cast<const bf16x8*>(Kh + byt);
            bf16x8 al = *reinterpret_cast<const bf16x8*>(Kl + byt);
            s0 = __builtin_amdgcn_mfma_f32_32x32x16_bf16(ah, Qh[ks], s0, 0, 0, 0);
            s1 = __builtin_amdgcn_mfma_f32_32x32x16_bf16(al, Qh[ks], s1, 0, 0, 0);
        }
        __builtin_amdgcn_s_setprio(0);
        f32x16 s = s0 + s1;

        float pmax = s[0];
        #pragma unroll
        for (int jj = 1; jj < 16; ++jj) pmax = fmaxf(pmax, s[jj]);
        pmax = fmaxf(pmax, __shfl_xor(pmax, 32));
        if (!__all(pmax - m <= 8.0f)) {
            const float mnew = fmaxf(m, pmax);
            const float corr = __expf(m - mnew);
            l *= corr;
            #pragma unroll
            for (int dt = 0; dt < 4; ++dt) oacc[dt] *= corr;
            m = mnew;
        }
        float psum = 0.f;
        #pragma unroll
        for (int jj = 0; jj < 16; ++jj) {
            float pv = __expf(s[jj] - m);
            s[jj] = pv;
            psum += pv;
        }
        psum += __shfl_xor(psum, 32);
        l += psum;

        #pragma unroll
        for (int ks = 0; ks < 2; ++ks) {
            const int b0 = ks * 8;
            uint wa = cvtpk(s[b0 + 0], s[b0 + 1]);
            uint wb = cvtpk(s[b0 + 2], s[b0 + 3]);
            uint wc = cvtpk(s[b0 + 4], s[b0 + 5]);
            uint wd = cvtpk(s[b0 + 6], s[b0 + 7]);
            permswap(wa, wc); permswap(wb, wd);
            bf16x8 Pf = pack4(wa, wb, wc, wd);
            __builtin_amdgcn_s_setprio(1);
            #pragma unroll
            for (int dt = 0; dt < 4; ++dt) {
                const int row = dt * 32 + ln31;
                const int byt = row * 64 + ((ks * 32 + hi * 16) ^ ((row & 3) << 4));
                bf16x8 vh = *reinterpret_cast<const bf16x8*>(Vh + byt);
                oacc[dt] = __builtin_amdgcn_mfma_f32_32x32x16_bf16(vh, Pf, oacc[dt], 0, 0, 0);
            }
            __builtin_amdgcn_s_setprio(0);
        }
    }

    // ---- epilogue: O -> bf16 hi only, packed layout for gemm_out6 ----
    const float invl = 1.0f / l;
    const int p   = q >> 7;
    const int rr_ = q & 127;
    const int rsw = (rr_ >> 1) & 3;
    #pragma unroll
    for (int dt = 0; dt < 4; ++dt) {
        const int kb = h * 4 + dt;
        uint16_t* bh = aoh + ((size_t)p * 128 + kb) * 4096;
        #pragma unroll
        for (int g4 = 0; g4 < 4; ++g4) {
            bf16x4 hv;
            #pragma unroll
            for (int e = 0; e < 4; ++e)
                hv[e] = (bf16_t)(oacc[dt][g4 * 4 + e] * invl);
            const int pos = rr_ * 32 + ((g4 ^ rsw) << 3) + 4 * hi;
            *reinterpret_cast<bf16x4*>(&bh[pos]) = hv;
        }
    }
}

extern "C" void kernel_launch(void* const* d_in, const int* in_sizes, int n_in,
                              void* d_out, int out_size, void* d_ws, size_t ws_size,
                              hipStream_t stream)
{
    const float* x  = (const float*)d_in[0];
    const float* wq = (const float*)d_in[1];
    const float* wk = (const float*)d_in[2];
    const float* wv = (const float*)d_in[3];
    const float* wo = (const float*)d_in[4];
    float* out = (float*)d_out;

    float* ws = (float*)d_ws;
    float*    xq   = ws;                           // [0, 8388608)
    uint16_t* kvg  = (uint16_t*)(ws + 8388608);    // [8388608, 11534336)
    float*    xk   = ws + 12582912;
    float*    xv   = ws + 14680064;
    uint16_t* aoh  = (uint16_t*)(ws + 12582912);   // reuses xk slot after conv_kv
    uint16_t* xh   = (uint16_t*)(ws + 20971520);
    uint16_t* xl   = (uint16_t*)(ws + 25165824);
    uint16_t* wqkv = (uint16_t*)(ws + 29360128);
    uint16_t* woh  = (uint16_t*)(ws + 41943040);

    dim3 blk(256);
    repack_hl <<<dim3(128, 16), blk, 0, stream>>>(x, xh, xl);
    repack_w96<<<dim3(128, 64), blk, 0, stream>>>(wq, wk, wv, wqkv);
    gemm_qkv4 <<<dim3(256), dim3(512), 0, stream>>>(xh, xl, wqkv, xq, xk, xv);
    repack_h  <<<dim3(128, 32), blk, 0, stream>>>(wo, woh);
    rope_k    <<<dim3(20480), blk, 0, stream>>>(xq, xk);
    conv_kv   <<<dim3(64, 8), blk, 0, stream>>>(xk, xv, kvg);
    attn_mfma <<<dim3(256), dim3(512), 0, stream>>>(xq, kvg, aoh);
    gemm_out6 <<<dim3(256), dim3(512), 0, stream>>>(aoh, woh, out);
}

// Round 11
// 395.808 us; speedup vs baseline: 1.3177x; 1.1642x over previous
//
#include <hip/hip_runtime.h>
#include <hip/hip_bf16.h>

typedef __bf16 bf16_t;
typedef _Float16 f16_t;
typedef unsigned int uint;
typedef __attribute__((ext_vector_type(8))) __bf16 bf16x8;
typedef __attribute__((ext_vector_type(4))) __bf16 bf16x4;
typedef __attribute__((ext_vector_type(8))) _Float16 f16x8;
typedef __attribute__((ext_vector_type(4))) _Float16 f16x4;
typedef __attribute__((ext_vector_type(4))) float f32x4;
typedef __attribute__((ext_vector_type(16))) float f32x16;

// ---------------- repack fp32 [R][4096] -> packed fp16 [R/128][128 kb][128 r][32 c] ----------------
// Bank swizzle baked in: elem pos = r*32 + ((slot ^ ((r>>1)&3))<<3) + (c&7), slot = c>>3.
__global__ __launch_bounds__(256) void repack_x16(const float* __restrict__ src,
                                                  uint16_t* __restrict__ dh)
{
    const int p  = blockIdx.y;
    const int kb = blockIdx.x;
    const int tid = threadIdx.x;
    const int rr = tid >> 3;
    const int k4 = tid & 7;
    const int slot = k4 >> 1;
    const int so   = (k4 & 1) * 4;
    uint16_t* bh = dh + ((size_t)p * 128 + kb) * 4096;
    #pragma unroll
    for (int it = 0; it < 4; ++it) {
        const int r = it * 32 + rr;
        const float4 v = *reinterpret_cast<const float4*>(
            &src[((size_t)p * 128 + r) * 4096 + kb * 32 + k4 * 4]);
        float f[4] = {v.x, v.y, v.z, v.w};
        f16x4 h;
        #pragma unroll
        for (int e = 0; e < 4; ++e) h[e] = (f16_t)f[e];
        const int pos = r * 32 + ((slot ^ ((r >> 1) & 3)) << 3) + so;
        *reinterpret_cast<f16x4*>(&bh[pos]) = h;
    }
}

// combined wq|wk|wv -> 96-row-panel packed fp16: [64 pan][128 kb][96 r][32 c]
__global__ __launch_bounds__(256) void repack_w96_16(const float* __restrict__ wq,
                                                     const float* __restrict__ wk,
                                                     const float* __restrict__ wv,
                                                     uint16_t* __restrict__ dst)
{
    const int kb  = blockIdx.x;
    const int pan = blockIdx.y;
    const int tid = threadIdx.x;
    const int k4 = tid & 7;
    const int slot = k4 >> 1;
    const int so   = (k4 & 1) * 4;
    uint16_t* bh = dst + ((size_t)pan * 128 + kb) * 3072;
    #pragma unroll
    for (int it = 0; it < 3; ++it) {
        const int r = it * 32 + (tid >> 3);
        const int n = pan * 96 + r;
        const float* srow = (n < 4096) ? (wq + (size_t)n * 4096)
                          : (n < 5120) ? (wk + (size_t)(n - 4096) * 4096)
                                       : (wv + (size_t)(n - 5120) * 4096);
        const float4 v = *reinterpret_cast<const float4*>(srow + kb * 32 + k4 * 4);
        float f[4] = {v.x, v.y, v.z, v.w};
        f16x4 h;
        #pragma unroll
        for (int e = 0; e < 4; ++e) h[e] = (f16_t)f[e];
        const int pos = r * 32 + ((slot ^ ((r >> 1) & 3)) << 3) + so;
        *reinterpret_cast<f16x4*>(&bh[pos]) = h;
    }
}

// 128-row-panel fp16 repack (wo)
__global__ __launch_bounds__(256) void repack_h16(const float* __restrict__ src,
                                                  uint16_t* __restrict__ dh)
{
    const int p  = blockIdx.y;
    const int kb = blockIdx.x;
    const int tid = threadIdx.x;
    const int rr = tid >> 3;
    const int k4 = tid & 7;
    const int slot = k4 >> 1;
    const int so   = (k4 & 1) * 4;
    uint16_t* bh = dh + ((size_t)p * 128 + kb) * 4096;
    #pragma unroll
    for (int it = 0; it < 4; ++it) {
        const int r = it * 32 + rr;
        const float4 v = *reinterpret_cast<const float4*>(
            &src[((size_t)p * 128 + r) * 4096 + kb * 32 + k4 * 4]);
        float f[4] = {v.x, v.y, v.z, v.w};
        f16x4 h;
        #pragma unroll
        for (int e = 0; e < 4; ++e) h[e] = (f16_t)f[e];
        const int pos = r * 32 + ((slot ^ ((r >> 1) & 3)) << 3) + so;
        *reinterpret_cast<f16x4*>(&bh[pos]) = h;
    }
}

// ---------------- QKV GEMM: 256x192, fp16 1-pass, 8 waves, BK=32, 3-buf depth-2, counted vmcnt ----------------
__global__ __launch_bounds__(512) void gemm_qkv7(const uint16_t* __restrict__ xh,
                                                 const uint16_t* __restrict__ wqkv,
                                                 float* __restrict__ xq,
                                                 float* __restrict__ xk,
                                                 float* __restrict__ xv)
{
    __shared__ char lds[3][28672];   // per buf: A 16K | B 12K

    const int bid = blockIdx.x;
    const int swz = (bid & 7) * 32 + (bid >> 3);
    const int by = swz >> 5;
    const int bx = swz & 31;
    const int tid = threadIdx.x;
    const int w = tid >> 6, lane = tid & 63;
    const int wm = w >> 2, wn = w & 3;
    const int fr = lane & 15, s4 = lane >> 4;

    // 28 chunks: 0..15 A, 16..27 B. waves 0-3: 4 chunks, waves 4-7: 3.
    const int cw = (w < 4) ? 4 : 3;
    const uint16_t* sp[4];
    int dof[4];
    int stridec[4];
    #pragma unroll
    for (int i = 0; i < 4; ++i) {
        const int c = w + 8 * i;
        if (c < 16) {
            sp[i] = xh + (size_t)(2 * by + (c >> 3)) * 524288 + (c & 7) * 512 + lane * 8;
            dof[i] = c * 1024;
            stridec[i] = 4096;
        } else {
            const int cb = (c - 16) % 12;
            sp[i] = wqkv + (size_t)(bx * 2 + (cb >= 6 ? 1 : 0)) * 393216 + (cb % 6) * 512 + lane * 8;
            dof[i] = 16384 + cb * 1024;
            stridec[i] = 3072;
        }
    }

    f32x4 acc[8][3] = {};

    #pragma unroll
    for (int i = 0; i < 4; ++i)
        if (i < cw)
            __builtin_amdgcn_global_load_lds(
                (const __attribute__((address_space(1))) void*)(sp[i]),
                (__attribute__((address_space(3))) void*)(&lds[0][0] + dof[i]), 16, 0, 0);
    #pragma unroll
    for (int i = 0; i < 4; ++i)
        if (i < cw)
            __builtin_amdgcn_global_load_lds(
                (const __attribute__((address_space(1))) void*)(sp[i] + stridec[i]),
                (__attribute__((address_space(3))) void*)(&lds[1][0] + dof[i]), 16, 0, 0);
    if (w < 4) asm volatile("s_waitcnt vmcnt(4)" ::: "memory");
    else       asm volatile("s_waitcnt vmcnt(3)" ::: "memory");
    __builtin_amdgcn_s_barrier();
    __builtin_amdgcn_sched_barrier(0);

    int cur = 0;
    for (int t = 0; t < 128; ++t) {
        if (t + 2 < 128) {
            int nb = cur + 2; if (nb >= 3) nb -= 3;
            #pragma unroll
            for (int i = 0; i < 4; ++i)
                if (i < cw)
                    __builtin_amdgcn_global_load_lds(
                        (const __attribute__((address_space(1))) void*)(sp[i] + (size_t)(t + 2) * stridec[i]),
                        (__attribute__((address_space(3))) void*)(&lds[nb][0] + dof[i]), 16, 0, 0);
        }
        const char* b = &lds[cur][0];

        f16x8 fb[3];
        #pragma unroll
        for (int j = 0; j < 3; ++j) {
            const int cbp = wn * 48 + j * 16 + fr;
            const int pan = (cbp >= 96) ? 1 : 0;
            const int rb = cbp - pan * 96;
            fb[j] = *reinterpret_cast<const f16x8*>(b + 16384 + pan * 6144 + rb * 64 + ((s4 ^ ((rb >> 1) & 3)) << 4));
        }
        #pragma unroll
        for (int p = 0; p < 4; ++p) {
            f16x8 fh[2];
            #pragma unroll
            for (int f = 0; f < 2; ++f) {
                const int rl = wm * 128 + p * 32 + f * 16 + fr;
                fh[f] = *reinterpret_cast<const f16x8*>(b + rl * 64 + ((s4 ^ ((rl >> 1) & 3)) << 4));
            }
            __builtin_amdgcn_s_setprio(1);
            #pragma unroll
            for (int f = 0; f < 2; ++f)
                #pragma unroll
                for (int j = 0; j < 3; ++j)
                    acc[p * 2 + f][j] = __builtin_amdgcn_mfma_f32_16x16x32_f16(fh[f], fb[j], acc[p * 2 + f][j], 0, 0, 0);
            __builtin_amdgcn_s_setprio(0);
        }
        if (t + 2 < 128) {
            if (w < 4) asm volatile("s_waitcnt vmcnt(4)" ::: "memory");
            else       asm volatile("s_waitcnt vmcnt(3)" ::: "memory");
        } else {
            asm volatile("s_waitcnt vmcnt(0)" ::: "memory");
        }
        __builtin_amdgcn_s_barrier();
        __builtin_amdgcn_sched_barrier(0);
        if (++cur == 3) cur = 0;
    }

    const int r0 = by * 256 + wm * 128 + s4 * 4;
    const int c0 = bx * 192 + wn * 48 + fr;
    #pragma unroll
    for (int ri = 0; ri < 8; ++ri)
        #pragma unroll
        for (int j = 0; j < 3; ++j) {
            const int col = c0 + j * 16;
            #pragma unroll
            for (int rr = 0; rr < 4; ++rr) {
                const int row = r0 + ri * 16 + rr;
                if (col < 4096)      xq[(size_t)row * 4096 + col] = acc[ri][j][rr];
                else if (col < 5120) xk[(size_t)row * 1024 + (col - 4096)] = acc[ri][j][rr];
                else                 xv[(size_t)row * 1024 + (col - 5120)] = acc[ri][j][rr];
            }
        }
}

// ---------------- Output GEMM: 256x128, fp16 1-pass, 3-buf depth-2, counted vmcnt ----------------
__global__ __launch_bounds__(512) void gemm_out7(const uint16_t* __restrict__ aoh,
                                                 const uint16_t* __restrict__ woh,
                                                 float* __restrict__ out)
{
    __shared__ char lds[3][24576];   // per buf: A 16K | B 8K

    const int bid = blockIdx.x;
    const int swz = (bid & 7) * 32 + (bid >> 3);
    const int by = swz >> 5;
    const int bx = swz & 31;
    const int tid = threadIdx.x;
    const int w = tid >> 6, lane = tid & 63;
    const int wm = w >> 2, wn = w & 3;
    const int fr = lane & 15, s4 = lane >> 4;

    const uint16_t* sp[3];
    int dof[3];
    #pragma unroll
    for (int i = 0; i < 3; ++i) {
        const int c = w + 8 * i;       // 0..23
        if (c < 16) {
            sp[i]  = aoh + (size_t)(2 * by + (c >> 3)) * 524288 + (c & 7) * 512 + lane * 8;
            dof[i] = c * 1024;
        } else {
            sp[i]  = woh + (size_t)bx * 524288 + (c - 16) * 512 + lane * 8;
            dof[i] = 16384 + (c - 16) * 1024;
        }
    }

    f32x4 acc[8][2] = {};

    #pragma unroll
    for (int i = 0; i < 3; ++i)
        __builtin_amdgcn_global_load_lds(
            (const __attribute__((address_space(1))) void*)(sp[i]),
            (__attribute__((address_space(3))) void*)(&lds[0][0] + dof[i]), 16, 0, 0);
    #pragma unroll
    for (int i = 0; i < 3; ++i)
        __builtin_amdgcn_global_load_lds(
            (const __attribute__((address_space(1))) void*)(sp[i] + 4096),
            (__attribute__((address_space(3))) void*)(&lds[1][0] + dof[i]), 16, 0, 0);
    asm volatile("s_waitcnt vmcnt(3)" ::: "memory");
    __builtin_amdgcn_s_barrier();
    __builtin_amdgcn_sched_barrier(0);

    int cur = 0;
    for (int t = 0; t < 128; ++t) {
        if (t + 2 < 128) {
            int nb = cur + 2; if (nb >= 3) nb -= 3;
            #pragma unroll
            for (int i = 0; i < 3; ++i)
                __builtin_amdgcn_global_load_lds(
                    (const __attribute__((address_space(1))) void*)(sp[i] + (size_t)(t + 2) * 4096),
                    (__attribute__((address_space(3))) void*)(&lds[nb][0] + dof[i]), 16, 0, 0);
        }
        const char* b = &lds[cur][0];

        f16x8 fb[2];
        #pragma unroll
        for (int j = 0; j < 2; ++j) {
            const int cbp = wn * 32 + j * 16 + fr;
            fb[j] = *reinterpret_cast<const f16x8*>(b + 16384 + cbp * 64 + ((s4 ^ ((cbp >> 1) & 3)) << 4));
        }
        #pragma unroll
        for (int p = 0; p < 4; ++p) {
            f16x8 fh[2];
            #pragma unroll
            for (int f = 0; f < 2; ++f) {
                const int rl = p * 32 + f * 16 + fr;
                fh[f] = *reinterpret_cast<const f16x8*>(b + wm * 8192 + rl * 64 + ((s4 ^ ((rl >> 1) & 3)) << 4));
            }
            __builtin_amdgcn_s_setprio(1);
            #pragma unroll
            for (int f = 0; f < 2; ++f)
                #pragma unroll
                for (int j = 0; j < 2; ++j)
                    acc[p * 2 + f][j] = __builtin_amdgcn_mfma_f32_16x16x32_f16(fh[f], fb[j], acc[p * 2 + f][j], 0, 0, 0);
            __builtin_amdgcn_s_setprio(0);
        }
        if (t + 2 < 128) asm volatile("s_waitcnt vmcnt(3)" ::: "memory");
        else             asm volatile("s_waitcnt vmcnt(0)" ::: "memory");
        __builtin_amdgcn_s_barrier();
        __builtin_amdgcn_sched_barrier(0);
        if (++cur == 3) cur = 0;
    }

    const int r0 = by * 256 + wm * 128 + s4 * 4;
    const int c0 = bx * 128 + wn * 32 + fr;
    #pragma unroll
    for (int ri = 0; ri < 8; ++ri)
        #pragma unroll
        for (int j = 0; j < 2; ++j)
            #pragma unroll
            for (int rr = 0; rr < 4; ++rr)
                out[(size_t)(r0 + ri * 16 + rr) * 4096 + c0 + j * 16] = acc[ri][j][rr];
}

// ---------------- RoPE in place; Q additionally scaled by 1/sqrt(128) ----------------
__global__ __launch_bounds__(256) void rope_k(float* __restrict__ xq, float* __restrict__ xk)
{
    const int idx = blockIdx.x * 256 + threadIdx.x;
    const int TOTQ = 2048 * 32 * 64;
    int s, j;
    float* base;
    bool isq = idx < TOTQ;
    if (isq) {
        s = idx >> 11;
        const int rem = idx & 2047;
        j = rem & 63;
        base = xq + (size_t)s * 4096 + (rem >> 6) * 128 + 2 * j;
    } else {
        const int i2 = idx - TOTQ;
        s = i2 >> 9;
        const int rem = i2 & 511;
        j = rem & 63;
        base = xk + (size_t)s * 1024 + (rem >> 6) * 128 + 2 * j;
    }
    const float invf = exp2f(-(float)j * (13.287712379549449f / 64.0f));
    const float ang = (float)s * invf;
    float sn, cs;
    sincosf(ang, &sn, &cs);
    float2 v = *reinterpret_cast<float2*>(base);
    float2 r;
    r.x = v.x * cs - v.y * sn;
    r.y = v.x * sn + v.y * cs;
    if (isq) { r.x *= 0.08838834764831845f; r.y *= 0.08838834764831845f; }
    *reinterpret_cast<float2*>(base) = r;
}

// ---------------- Convert roped K (hi+lo) and raw V (hi only) to blocked+swizzled bf16 tiles ----------------
__global__ __launch_bounds__(256) void conv_kv(const float* __restrict__ xk,
                                               const float* __restrict__ xv,
                                               uint16_t* __restrict__ kvg)
{
    __shared__ float V[32][129];
    const int t = blockIdx.x;
    const int h = blockIdx.y;
    const int tid = threadIdx.x;
    uint16_t* tile = kvg + ((size_t)(h * 64 + t)) * 12288;

    #pragma unroll
    for (int i = 0; i < 4; ++i) {
        int v = i * 256 + tid;
        int row = v >> 5, c4 = (v & 31) * 4;
        *reinterpret_cast<float4*>(&V[row][c4]) =
            *reinterpret_cast<const float4*>(&xv[(size_t)(t * 32 + row) * 1024 + h * 128 + c4]);
    }

    {
        const int r = tid >> 3;
        const int d0 = (tid & 7) * 16;
        float f[16];
        const float* kr = &xk[(size_t)(t * 32 + r) * 1024 + h * 128 + d0];
        *reinterpret_cast<float4*>(&f[0])  = *reinterpret_cast<const float4*>(kr);
        *reinterpret_cast<float4*>(&f[4])  = *reinterpret_cast<const float4*>(kr + 4);
        *reinterpret_cast<float4*>(&f[8])  = *reinterpret_cast<const float4*>(kr + 8);
        *reinterpret_cast<float4*>(&f[12]) = *reinterpret_cast<const float4*>(kr + 12);
        #pragma unroll
        for (int cc = 0; cc < 2; ++cc) {
            bf16x8 hv, lv;
            #pragma unroll
            for (int e = 0; e < 8; ++e) {
                float x = f[cc * 8 + e];
                bf16_t hb = (bf16_t)x;
                hv[e] = hb;
                lv[e] = (bf16_t)(x - (float)hb);
            }
            const int c = (d0 >> 3) + cc;
            const int pos = r * 128 + ((c ^ (r & 15)) << 3);
            *reinterpret_cast<bf16x8*>(&tile[pos]) = hv;
            *reinterpret_cast<bf16x8*>(&tile[4096 + pos]) = lv;
        }
    }
    __syncthreads();
    {
        const int d = tid >> 1;
        const int k0 = (tid & 1) * 16;
        float g[16];
        #pragma unroll
        for (int j = 0; j < 16; ++j) g[j] = V[k0 + j][d];
        #pragma unroll
        for (int cc = 0; cc < 2; ++cc) {
            bf16x8 hv;
            #pragma unroll
            for (int e = 0; e < 8; ++e) hv[e] = (bf16_t)g[cc * 8 + e];
            const int c = (k0 >> 3) + cc;
            const int pos = d * 32 + ((c ^ (d & 3)) << 3);
            *reinterpret_cast<bf16x8*>(&tile[8192 + pos]) = hv;
        }
    }
}

// ---------------- MFMA flash attention (split QK chains, 1-pass PV, defer-max, fp16 packed epilogue) ----------------
__device__ __forceinline__ uint cvtpk(float lo, float hi) {
    uint r;
    asm("v_cvt_pk_bf16_f32 %0, %1, %2" : "=v"(r) : "v"(lo), "v"(hi));
    return r;
}
__device__ __forceinline__ void permswap(uint& a, uint& b) {
    asm("v_permlane32_swap_b32 %0, %1" : "+v"(a), "+v"(b));
}
__device__ __forceinline__ bf16x8 pack4(uint w0, uint w1, uint w2, uint w3) {
    union { uint u[4]; bf16x8 v; } t;
    t.u[0] = w0; t.u[1] = w1; t.u[2] = w2; t.u[3] = w3;
    return t.v;
}

__global__ __launch_bounds__(512, 2) void attn_mfma(const float* __restrict__ xq,
                                                    const uint16_t* __restrict__ kvg,
                                                    uint16_t* __restrict__ aoh)
{
    __shared__ char lds[2][24576];

    const int b = blockIdx.x;
    const int kvh = b & 7;
    const int r = b >> 3;
    const int h = kvh * 4 + (r & 3);
    const int q0 = (r >> 2) * 256;
    const int tid = threadIdx.x;
    const int w = tid >> 6;
    const int lane = tid & 63;
    const int ln31 = lane & 31;
    const int hi = lane >> 5;

    const int q = q0 + w * 32 + ln31;
    const float* qrow = xq + (size_t)q * 4096 + h * 128;
    bf16x8 Qh[8];
    #pragma unroll
    for (int ks = 0; ks < 8; ++ks) {
        float f[8];
        *reinterpret_cast<float4*>(&f[0]) = *reinterpret_cast<const float4*>(qrow + ks * 16 + hi * 8);
        *reinterpret_cast<float4*>(&f[4]) = *reinterpret_cast<const float4*>(qrow + ks * 16 + hi * 8 + 4);
        #pragma unroll
        for (int e = 0; e < 8; ++e) Qh[ks][e] = (bf16_t)f[e];
    }

    const char* gkv = (const char*)kvg + (size_t)kvh * 64 * 24576;

    f32x16 oacc[4] = {{}, {}, {}, {}};
    float m = -3.0e38f, l = 0.f;

    {
        #pragma unroll
        for (int i = 0; i < 3; ++i) {
            const int chunk = i * 8 + w;
            __builtin_amdgcn_global_load_lds(
                (const __attribute__((address_space(1))) void*)(gkv + chunk * 1024 + lane * 16),
                (__attribute__((address_space(3))) void*)(&lds[0][chunk * 1024]),
                16, 0, 0);
        }
    }

    for (int t = 0; t < 64; ++t) {
        __syncthreads();
        if (t + 1 < 64) {
            const char* g = gkv + (size_t)(t + 1) * 24576;
            const int buf = (t + 1) & 1;
            #pragma unroll
            for (int i = 0; i < 3; ++i) {
                const int chunk = i * 8 + w;
                __builtin_amdgcn_global_load_lds(
                    (const __attribute__((address_space(1))) void*)(g + chunk * 1024 + lane * 16),
                    (__attribute__((address_space(3))) void*)(&lds[buf][chunk * 1024]),
                    16, 0, 0);
            }
        }
        const int cur = t & 1;
        const char* Kh = lds[cur];
        const char* Kl = lds[cur] + 8192;
        const char* Vh = lds[cur] + 16384;

        f32x16 s0 = {}, s1 = {};
        __builtin_amdgcn_s_setprio(1);
        #pragma unroll
        for (int ks = 0; ks < 8; ++ks) {
            const int byt = ln31 * 256 + ((ks * 32 + hi * 16) ^ ((ln31 & 15) << 4));
            bf16x8 ah = *reinterpret_cast<const bf16x8*>(Kh + byt);
            bf16x8 al = *reinterpret_cast<const bf16x8*>(Kl + byt);
            s0 = __builtin_amdgcn_mfma_f32_32x32x16_bf16(ah, Qh[ks], s0, 0, 0, 0);
            s1 = __builtin_amdgcn_mfma_f32_32x32x16_bf16(al, Qh[ks], s1, 0, 0, 0);
        }
        __builtin_amdgcn_s_setprio(0);
        f32x16 s = s0 + s1;

        float pmax = s[0];
        #pragma unroll
        for (int jj = 1; jj < 16; ++jj) pmax = fmaxf(pmax, s[jj]);
        pmax = fmaxf(pmax, __shfl_xor(pmax, 32));
        if (!__all(pmax - m <= 8.0f)) {
            const float mnew = fmaxf(m, pmax);
            const float corr = __expf(m - mnew);
            l *= corr;
            #pragma unroll
            for (int dt = 0; dt < 4; ++dt) oacc[dt] *= corr;
            m = mnew;
        }
        float psum = 0.f;
        #pragma unroll
        for (int jj = 0; jj < 16; ++jj) {
            float pv = __expf(s[jj] - m);
            s[jj] = pv;
            psum += pv;
        }
        psum += __shfl_xor(psum, 32);
        l += psum;

        #pragma unroll
        for (int ks = 0; ks < 2; ++ks) {
            const int b0 = ks * 8;
            uint wa = cvtpk(s[b0 + 0], s[b0 + 1]);
            uint wb = cvtpk(s[b0 + 2], s[b0 + 3]);
            uint wc = cvtpk(s[b0 + 4], s[b0 + 5]);
            uint wd = cvtpk(s[b0 + 6], s[b0 + 7]);
            permswap(wa, wc); permswap(wb, wd);
            bf16x8 Pf = pack4(wa, wb, wc, wd);
            __builtin_amdgcn_s_setprio(1);
            #pragma unroll
            for (int dt = 0; dt < 4; ++dt) {
                const int row = dt * 32 + ln31;
                const int byt = row * 64 + ((ks * 32 + hi * 16) ^ ((row & 3) << 4));
                bf16x8 vh = *reinterpret_cast<const bf16x8*>(Vh + byt);
                oacc[dt] = __builtin_amdgcn_mfma_f32_32x32x16_bf16(vh, Pf, oacc[dt], 0, 0, 0);
            }
            __builtin_amdgcn_s_setprio(0);
        }
    }

    // ---- epilogue: O -> fp16, packed layout for gemm_out7 ----
    const float invl = 1.0f / l;
    const int p   = q >> 7;
    const int rr_ = q & 127;
    const int rsw = (rr_ >> 1) & 3;
    #pragma unroll
    for (int dt = 0; dt < 4; ++dt) {
        const int kb = h * 4 + dt;
        uint16_t* bh = aoh + ((size_t)p * 128 + kb) * 4096;
        #pragma unroll
        for (int g4 = 0; g4 < 4; ++g4) {
            f16x4 hv;
            #pragma unroll
            for (int e = 0; e < 4; ++e)
                hv[e] = (f16_t)(oacc[dt][g4 * 4 + e] * invl);
            const int pos = rr_ * 32 + ((g4 ^ rsw) << 3) + 4 * hi;
            *reinterpret_cast<f16x4*>(&bh[pos]) = hv;
        }
    }
}

extern "C" void kernel_launch(void* const* d_in, const int* in_sizes, int n_in,
                              void* d_out, int out_size, void* d_ws, size_t ws_size,
                              hipStream_t stream)
{
    const float* x  = (const float*)d_in[0];
    const float* wq = (const float*)d_in[1];
    const float* wk = (const float*)d_in[2];
    const float* wv = (const float*)d_in[3];
    const float* wo = (const float*)d_in[4];
    float* out = (float*)d_out;

    float* ws = (float*)d_ws;
    float*    xq   = ws;                           // [0, 8388608)
    uint16_t* kvg  = (uint16_t*)(ws + 8388608);    // [8388608, 11534336)
    float*    xk   = ws + 12582912;
    float*    xv   = ws + 14680064;
    uint16_t* aoh  = (uint16_t*)(ws + 12582912);   // reuses xk slot after conv_kv
    uint16_t* xh   = (uint16_t*)(ws + 20971520);   // fp16 packed x (8.4M elems)
    uint16_t* wqkv = (uint16_t*)(ws + 29360128);   // fp16 packed wq|wk|wv (25.2M elems)
    uint16_t* woh  = (uint16_t*)(ws + 41943040);   // fp16 packed wo (16.8M elems)

    dim3 blk(256);
    repack_x16   <<<dim3(128, 16), blk, 0, stream>>>(x, xh);
    repack_w96_16<<<dim3(128, 64), blk, 0, stream>>>(wq, wk, wv, wqkv);
    gemm_qkv7    <<<dim3(256), dim3(512), 0, stream>>>(xh, wqkv, xq, xk, xv);
    repack_h16   <<<dim3(128, 32), blk, 0, stream>>>(wo, woh);
    rope_k       <<<dim3(20480), blk, 0, stream>>>(xq, xk);
    conv_kv      <<<dim3(64, 8), blk, 0, stream>>>(xk, xv, kvg);
    attn_mfma    <<<dim3(256), dim3(512), 0, stream>>>(xq, kvg, aoh);
    gemm_out7    <<<dim3(256), dim3(512), 0, stream>>>(aoh, woh, out);
}

// Round 12
// 371.779 us; speedup vs baseline: 1.4029x; 1.0646x over previous
//
#include <hip/hip_runtime.h>
#include <hip/hip_bf16.h>

typedef _Float16 f16_t;
typedef unsigned int uint;
typedef __attribute__((ext_vector_type(8))) _Float16 f16x8;
typedef __attribute__((ext_vector_type(4))) _Float16 f16x4;
typedef __attribute__((ext_vector_type(4))) float f32x4;
typedef __attribute__((ext_vector_type(16))) float f32x16;

// ---------------- repack fp32 [R][4096] -> packed fp16 [R/128][128 kb][128 r][32 c] ----------------
// Bank swizzle baked in: elem pos = r*32 + ((slot ^ ((r>>1)&3))<<3) + (c&7), slot = c>>3.
__global__ __launch_bounds__(256) void repack_x16(const float* __restrict__ src,
                                                  uint16_t* __restrict__ dh)
{
    const int p  = blockIdx.y;
    const int kb = blockIdx.x;
    const int tid = threadIdx.x;
    const int rr = tid >> 3;
    const int k4 = tid & 7;
    const int slot = k4 >> 1;
    const int so   = (k4 & 1) * 4;
    uint16_t* bh = dh + ((size_t)p * 128 + kb) * 4096;
    #pragma unroll
    for (int it = 0; it < 4; ++it) {
        const int r = it * 32 + rr;
        const float4 v = *reinterpret_cast<const float4*>(
            &src[((size_t)p * 128 + r) * 4096 + kb * 32 + k4 * 4]);
        float f[4] = {v.x, v.y, v.z, v.w};
        f16x4 h;
        #pragma unroll
        for (int e = 0; e < 4; ++e) h[e] = (f16_t)f[e];
        const int pos = r * 32 + ((slot ^ ((r >> 1) & 3)) << 3) + so;
        *reinterpret_cast<f16x4*>(&bh[pos]) = h;
    }
}

// combined wq|wk|wv -> 96-row-panel packed fp16: [64 pan][128 kb][96 r][32 c]
__global__ __launch_bounds__(256) void repack_w96_16(const float* __restrict__ wq,
                                                     const float* __restrict__ wk,
                                                     const float* __restrict__ wv,
                                                     uint16_t* __restrict__ dst)
{
    const int kb  = blockIdx.x;
    const int pan = blockIdx.y;
    const int tid = threadIdx.x;
    const int k4 = tid & 7;
    const int slot = k4 >> 1;
    const int so   = (k4 & 1) * 4;
    uint16_t* bh = dst + ((size_t)pan * 128 + kb) * 3072;
    #pragma unroll
    for (int it = 0; it < 3; ++it) {
        const int r = it * 32 + (tid >> 3);
        const int n = pan * 96 + r;
        const float* srow = (n < 4096) ? (wq + (size_t)n * 4096)
                          : (n < 5120) ? (wk + (size_t)(n - 4096) * 4096)
                                       : (wv + (size_t)(n - 5120) * 4096);
        const float4 v = *reinterpret_cast<const float4*>(srow + kb * 32 + k4 * 4);
        float f[4] = {v.x, v.y, v.z, v.w};
        f16x4 h;
        #pragma unroll
        for (int e = 0; e < 4; ++e) h[e] = (f16_t)f[e];
        const int pos = r * 32 + ((slot ^ ((r >> 1) & 3)) << 3) + so;
        *reinterpret_cast<f16x4*>(&bh[pos]) = h;
    }
}

// 128-row-panel fp16 repack (wo)
__global__ __launch_bounds__(256) void repack_h16(const float* __restrict__ src,
                                                  uint16_t* __restrict__ dh)
{
    const int p  = blockIdx.y;
    const int kb = blockIdx.x;
    const int tid = threadIdx.x;
    const int rr = tid >> 3;
    const int k4 = tid & 7;
    const int slot = k4 >> 1;
    const int so   = (k4 & 1) * 4;
    uint16_t* bh = dh + ((size_t)p * 128 + kb) * 4096;
    #pragma unroll
    for (int it = 0; it < 4; ++it) {
        const int r = it * 32 + rr;
        const float4 v = *reinterpret_cast<const float4*>(
            &src[((size_t)p * 128 + r) * 4096 + kb * 32 + k4 * 4]);
        float f[4] = {v.x, v.y, v.z, v.w};
        f16x4 h;
        #pragma unroll
        for (int e = 0; e < 4; ++e) h[e] = (f16_t)f[e];
        const int pos = r * 32 + ((slot ^ ((r >> 1) & 3)) << 3) + so;
        *reinterpret_cast<f16x4*>(&bh[pos]) = h;
    }
}

// ---------------- QKV GEMM: 256x192, fp16, BK=64, 2-buf, one barrier per K-step ----------------
__global__ __launch_bounds__(512) void gemm_qkv8(const uint16_t* __restrict__ xh,
                                                 const uint16_t* __restrict__ wqkv,
                                                 float* __restrict__ xq,
                                                 float* __restrict__ xk,
                                                 float* __restrict__ xv)
{
    __shared__ char lds[2][57344];   // per buf: A 32K ([pan2][kk2][128r][32c]) | B 24K ([pan2][kk2][96r][32c])

    const int bid = blockIdx.x;
    const int swz = (bid & 7) * 32 + (bid >> 3);
    const int by = swz >> 5;
    const int bx = swz & 31;
    const int tid = threadIdx.x;
    const int w = tid >> 6, lane = tid & 63;
    const int wm = w >> 2, wn = w & 3;
    const int fr = lane & 15, s4 = lane >> 4;

    // 56 chunks of 1 KB: 0..31 A, 32..55 B; wave w stages c = w + 8i, i=0..6
    const uint16_t* sp[7];
    int dof[7];
    int stridec[7];
    #pragma unroll
    for (int i = 0; i < 7; ++i) {
        const int c = w + 8 * i;
        if (c < 32) {
            const int pan = c >> 4, sub = c & 15;
            sp[i] = xh + (size_t)(2 * by + pan) * 524288 + sub * 512 + lane * 8;
            dof[i] = c * 1024;
            stridec[i] = 8192;
        } else {
            const int cb = c - 32;               // 0..23
            const int pan = cb / 12, sub = cb % 12;
            sp[i] = wqkv + (size_t)(bx * 2 + pan) * 393216 + sub * 512 + lane * 8;
            dof[i] = 32768 + cb * 1024;
            stridec[i] = 6144;
        }
    }

    f32x4 acc[8][3] = {};

    // prologue: stage tile 0
    #pragma unroll
    for (int i = 0; i < 7; ++i)
        __builtin_amdgcn_global_load_lds(
            (const __attribute__((address_space(1))) void*)(sp[i]),
            (__attribute__((address_space(3))) void*)(&lds[0][0] + dof[i]), 16, 0, 0);
    asm volatile("s_waitcnt vmcnt(0)" ::: "memory");
    __builtin_amdgcn_s_barrier();
    __builtin_amdgcn_sched_barrier(0);

    for (int t = 0; t < 64; ++t) {
        const char* b = &lds[t & 1][0];
        if (t + 1 < 64) {
            char* nb = &lds[(t + 1) & 1][0];
            #pragma unroll
            for (int i = 0; i < 7; ++i)
                __builtin_amdgcn_global_load_lds(
                    (const __attribute__((address_space(1))) void*)(sp[i] + (size_t)(t + 1) * stridec[i]),
                    (__attribute__((address_space(3))) void*)(nb + dof[i]), 16, 0, 0);
        }
        #pragma unroll
        for (int kk = 0; kk < 2; ++kk) {
            f16x8 fb[3];
            #pragma unroll
            for (int j = 0; j < 3; ++j) {
                const int cbp = wn * 48 + j * 16 + fr;
                const int pan = (cbp >= 96) ? 1 : 0;
                const int rb = cbp - pan * 96;
                fb[j] = *reinterpret_cast<const f16x8*>(
                    b + 32768 + pan * 12288 + kk * 6144 + rb * 64 + ((s4 ^ ((rb >> 1) & 3)) << 4));
            }
            #pragma unroll
            for (int p = 0; p < 4; ++p) {
                f16x8 fh[2];
                #pragma unroll
                for (int f = 0; f < 2; ++f) {
                    const int rloc = p * 32 + f * 16 + fr;   // 0..127 within pan=wm
                    fh[f] = *reinterpret_cast<const f16x8*>(
                        b + wm * 16384 + kk * 8192 + rloc * 64 + ((s4 ^ ((rloc >> 1) & 3)) << 4));
                }
                __builtin_amdgcn_s_setprio(1);
                #pragma unroll
                for (int f = 0; f < 2; ++f)
                    #pragma unroll
                    for (int j = 0; j < 3; ++j)
                        acc[p * 2 + f][j] = __builtin_amdgcn_mfma_f32_16x16x32_f16(fh[f], fb[j], acc[p * 2 + f][j], 0, 0, 0);
                __builtin_amdgcn_s_setprio(0);
            }
        }
        asm volatile("s_waitcnt vmcnt(0)" ::: "memory");
        __builtin_amdgcn_s_barrier();
        __builtin_amdgcn_sched_barrier(0);
    }

    const int r0 = by * 256 + wm * 128 + s4 * 4;
    const int c0 = bx * 192 + wn * 48 + fr;
    #pragma unroll
    for (int ri = 0; ri < 8; ++ri)
        #pragma unroll
        for (int j = 0; j < 3; ++j) {
            const int col = c0 + j * 16;
            #pragma unroll
            for (int rr = 0; rr < 4; ++rr) {
                const int row = r0 + ri * 16 + rr;
                if (col < 4096)      xq[(size_t)row * 4096 + col] = acc[ri][j][rr];
                else if (col < 5120) xk[(size_t)row * 1024 + (col - 4096)] = acc[ri][j][rr];
                else                 xv[(size_t)row * 1024 + (col - 5120)] = acc[ri][j][rr];
            }
        }
}

// ---------------- Output GEMM: 256x128, fp16, BK=64, 2-buf ----------------
__global__ __launch_bounds__(512) void gemm_out8(const uint16_t* __restrict__ aoh,
                                                 const uint16_t* __restrict__ woh,
                                                 float* __restrict__ out)
{
    __shared__ char lds[2][49152];   // A 32K | B 16K ([kk2][128r][32c])

    const int bid = blockIdx.x;
    const int swz = (bid & 7) * 32 + (bid >> 3);
    const int by = swz >> 5;
    const int bx = swz & 31;
    const int tid = threadIdx.x;
    const int w = tid >> 6, lane = tid & 63;
    const int wm = w >> 2, wn = w & 3;
    const int fr = lane & 15, s4 = lane >> 4;

    // 48 chunks: 0..31 A, 32..47 B; wave w stages c = w + 8i, i=0..5
    const uint16_t* sp[6];
    int dof[6];
    #pragma unroll
    for (int i = 0; i < 6; ++i) {
        const int c = w + 8 * i;
        if (c < 32) {
            const int pan = c >> 4, sub = c & 15;
            sp[i] = aoh + (size_t)(2 * by + pan) * 524288 + sub * 512 + lane * 8;
            dof[i] = c * 1024;
        } else {
            sp[i] = woh + (size_t)bx * 524288 + (c - 32) * 512 + lane * 8;
            dof[i] = 32768 + (c - 32) * 1024;
        }
    }

    f32x4 acc[8][2] = {};

    #pragma unroll
    for (int i = 0; i < 6; ++i)
        __builtin_amdgcn_global_load_lds(
            (const __attribute__((address_space(1))) void*)(sp[i]),
            (__attribute__((address_space(3))) void*)(&lds[0][0] + dof[i]), 16, 0, 0);
    asm volatile("s_waitcnt vmcnt(0)" ::: "memory");
    __builtin_amdgcn_s_barrier();
    __builtin_amdgcn_sched_barrier(0);

    for (int t = 0; t < 64; ++t) {
        const char* b = &lds[t & 1][0];
        if (t + 1 < 64) {
            char* nb = &lds[(t + 1) & 1][0];
            #pragma unroll
            for (int i = 0; i < 6; ++i)
                __builtin_amdgcn_global_load_lds(
                    (const __attribute__((address_space(1))) void*)(sp[i] + (size_t)(t + 1) * 8192),
                    (__attribute__((address_space(3))) void*)(nb + dof[i]), 16, 0, 0);
        }
        #pragma unroll
        for (int kk = 0; kk < 2; ++kk) {
            f16x8 fb[2];
            #pragma unroll
            for (int j = 0; j < 2; ++j) {
                const int cbp = wn * 32 + j * 16 + fr;
                fb[j] = *reinterpret_cast<const f16x8*>(
                    b + 32768 + kk * 8192 + cbp * 64 + ((s4 ^ ((cbp >> 1) & 3)) << 4));
            }
            #pragma unroll
            for (int p = 0; p < 4; ++p) {
                f16x8 fh[2];
                #pragma unroll
                for (int f = 0; f < 2; ++f) {
                    const int rloc = p * 32 + f * 16 + fr;
                    fh[f] = *reinterpret_cast<const f16x8*>(
                        b + wm * 16384 + kk * 8192 + rloc * 64 + ((s4 ^ ((rloc >> 1) & 3)) << 4));
                }
                __builtin_amdgcn_s_setprio(1);
                #pragma unroll
                for (int f = 0; f < 2; ++f)
                    #pragma unroll
                    for (int j = 0; j < 2; ++j)
                        acc[p * 2 + f][j] = __builtin_amdgcn_mfma_f32_16x16x32_f16(fh[f], fb[j], acc[p * 2 + f][j], 0, 0, 0);
                __builtin_amdgcn_s_setprio(0);
            }
        }
        asm volatile("s_waitcnt vmcnt(0)" ::: "memory");
        __builtin_amdgcn_s_barrier();
        __builtin_amdgcn_sched_barrier(0);
    }

    const int r0 = by * 256 + wm * 128 + s4 * 4;
    const int c0 = bx * 128 + wn * 32 + fr;
    #pragma unroll
    for (int ri = 0; ri < 8; ++ri)
        #pragma unroll
        for (int j = 0; j < 2; ++j)
            #pragma unroll
            for (int rr = 0; rr < 4; ++rr)
                out[(size_t)(r0 + ri * 16 + rr) * 4096 + c0 + j * 16] = acc[ri][j][rr];
}

// ---------------- RoPE in place; Q additionally scaled by 1/sqrt(128) ----------------
__global__ __launch_bounds__(256) void rope_k(float* __restrict__ xq, float* __restrict__ xk)
{
    const int idx = blockIdx.x * 256 + threadIdx.x;
    const int TOTQ = 2048 * 32 * 64;
    int s, j;
    float* base;
    bool isq = idx < TOTQ;
    if (isq) {
        s = idx >> 11;
        const int rem = idx & 2047;
        j = rem & 63;
        base = xq + (size_t)s * 4096 + (rem >> 6) * 128 + 2 * j;
    } else {
        const int i2 = idx - TOTQ;
        s = i2 >> 9;
        const int rem = i2 & 511;
        j = rem & 63;
        base = xk + (size_t)s * 1024 + (rem >> 6) * 128 + 2 * j;
    }
    const float invf = exp2f(-(float)j * (13.287712379549449f / 64.0f));
    const float ang = (float)s * invf;
    float sn, cs;
    sincosf(ang, &sn, &cs);
    float2 v = *reinterpret_cast<float2*>(base);
    float2 r;
    r.x = v.x * cs - v.y * sn;
    r.y = v.x * sn + v.y * cs;
    if (isq) { r.x *= 0.08838834764831845f; r.y *= 0.08838834764831845f; }
    *reinterpret_cast<float2*>(base) = r;
}

// ---------------- Convert roped K and raw V to blocked+swizzled fp16 tiles ----------------
// Tile = 8192 uint16 (16 KB): K [32 kv][128 d] at 0, Vt [128 d][32 kv] at 4096.
__global__ __launch_bounds__(256) void conv_kv(const float* __restrict__ xk,
                                               const float* __restrict__ xv,
                                               uint16_t* __restrict__ kvg)
{
    __shared__ float V[32][129];
    const int t = blockIdx.x;
    const int h = blockIdx.y;
    const int tid = threadIdx.x;
    uint16_t* tile = kvg + ((size_t)(h * 64 + t)) * 8192;

    #pragma unroll
    for (int i = 0; i < 4; ++i) {
        int v = i * 256 + tid;
        int row = v >> 5, c4 = (v & 31) * 4;
        *reinterpret_cast<float4*>(&V[row][c4]) =
            *reinterpret_cast<const float4*>(&xv[(size_t)(t * 32 + row) * 1024 + h * 128 + c4]);
    }

    {
        const int r = tid >> 3;
        const int d0 = (tid & 7) * 16;
        float f[16];
        const float* kr = &xk[(size_t)(t * 32 + r) * 1024 + h * 128 + d0];
        *reinterpret_cast<float4*>(&f[0])  = *reinterpret_cast<const float4*>(kr);
        *reinterpret_cast<float4*>(&f[4])  = *reinterpret_cast<const float4*>(kr + 4);
        *reinterpret_cast<float4*>(&f[8])  = *reinterpret_cast<const float4*>(kr + 8);
        *reinterpret_cast<float4*>(&f[12]) = *reinterpret_cast<const float4*>(kr + 12);
        #pragma unroll
        for (int cc = 0; cc < 2; ++cc) {
            f16x8 hv;
            #pragma unroll
            for (int e = 0; e < 8; ++e) hv[e] = (f16_t)f[cc * 8 + e];
            const int c = (d0 >> 3) + cc;
            const int pos = r * 128 + ((c ^ (r & 15)) << 3);
            *reinterpret_cast<f16x8*>(&tile[pos]) = hv;
        }
    }
    __syncthreads();
    {
        const int d = tid >> 1;
        const int k0 = (tid & 1) * 16;
        float g[16];
        #pragma unroll
        for (int j = 0; j < 16; ++j) g[j] = V[k0 + j][d];
        #pragma unroll
        for (int cc = 0; cc < 2; ++cc) {
            f16x8 hv;
            #pragma unroll
            for (int e = 0; e < 8; ++e) hv[e] = (f16_t)g[cc * 8 + e];
            const int c = (k0 >> 3) + cc;
            const int pos = 4096 + d * 32 + ((c ^ (d & 3)) << 3);
            *reinterpret_cast<f16x8*>(&tile[pos]) = hv;
        }
    }
}

// ---------------- MFMA flash attention (full fp16: Q,K,V,P; defer-max; fp16 packed epilogue) ----------------
__device__ __forceinline__ uint cvtpkh(float lo, float hi) {
    uint r;
    asm("v_cvt_pkrtz_f16_f32 %0, %1, %2" : "=v"(r) : "v"(lo), "v"(hi));
    return r;
}
__device__ __forceinline__ void permswap(uint& a, uint& b) {
    asm("v_permlane32_swap_b32 %0, %1" : "+v"(a), "+v"(b));
}
__device__ __forceinline__ f16x8 pack4h(uint w0, uint w1, uint w2, uint w3) {
    union { uint u[4]; f16x8 v; } t;
    t.u[0] = w0; t.u[1] = w1; t.u[2] = w2; t.u[3] = w3;
    return t.v;
}

__global__ __launch_bounds__(512, 2) void attn_mfma(const float* __restrict__ xq,
                                                    const uint16_t* __restrict__ kvg,
                                                    uint16_t* __restrict__ aoh)
{
    __shared__ char lds[2][16384];

    const int b = blockIdx.x;
    const int kvh = b & 7;
    const int r = b >> 3;
    const int h = kvh * 4 + (r & 3);
    const int q0 = (r >> 2) * 256;
    const int tid = threadIdx.x;
    const int w = tid >> 6;
    const int lane = tid & 63;
    const int ln31 = lane & 31;
    const int hi = lane >> 5;

    const int q = q0 + w * 32 + ln31;
    const float* qrow = xq + (size_t)q * 4096 + h * 128;
    f16x8 Qh[8];
    #pragma unroll
    for (int ks = 0; ks < 8; ++ks) {
        float f[8];
        *reinterpret_cast<float4*>(&f[0]) = *reinterpret_cast<const float4*>(qrow + ks * 16 + hi * 8);
        *reinterpret_cast<float4*>(&f[4]) = *reinterpret_cast<const float4*>(qrow + ks * 16 + hi * 8 + 4);
        #pragma unroll
        for (int e = 0; e < 8; ++e) Qh[ks][e] = (f16_t)f[e];
    }

    const char* gkv = (const char*)kvg + (size_t)kvh * 64 * 16384;

    f32x16 oacc[4] = {{}, {}, {}, {}};
    float m = -3.0e38f, l = 0.f;

    {
        #pragma unroll
        for (int i = 0; i < 2; ++i) {
            const int chunk = i * 8 + w;
            __builtin_amdgcn_global_load_lds(
                (const __attribute__((address_space(1))) void*)(gkv + chunk * 1024 + lane * 16),
                (__attribute__((address_space(3))) void*)(&lds[0][chunk * 1024]),
                16, 0, 0);
        }
    }

    for (int t = 0; t < 64; ++t) {
        __syncthreads();
        if (t + 1 < 64) {
            const char* g = gkv + (size_t)(t + 1) * 16384;
            const int buf = (t + 1) & 1;
            #pragma unroll
            for (int i = 0; i < 2; ++i) {
                const int chunk = i * 8 + w;
                __builtin_amdgcn_global_load_lds(
                    (const __attribute__((address_space(1))) void*)(g + chunk * 1024 + lane * 16),
                    (__attribute__((address_space(3))) void*)(&lds[buf][chunk * 1024]),
                    16, 0, 0);
            }
        }
        const int cur = t & 1;
        const char* Kf = lds[cur];
        const char* Vf = lds[cur] + 8192;

        // ---- swapped QK^T: fp16 1-pass, two independent chains (even/odd ks) ----
        f32x16 s0 = {}, s1 = {};
        __builtin_amdgcn_s_setprio(1);
        #pragma unroll
        for (int ks = 0; ks < 8; ++ks) {
            const int byt = ln31 * 256 + ((ks * 32 + hi * 16) ^ ((ln31 & 15) << 4));
            f16x8 a = *reinterpret_cast<const f16x8*>(Kf + byt);
            if (ks & 1) s1 = __builtin_amdgcn_mfma_f32_32x32x16_f16(a, Qh[ks], s1, 0, 0, 0);
            else        s0 = __builtin_amdgcn_mfma_f32_32x32x16_f16(a, Qh[ks], s0, 0, 0, 0);
        }
        __builtin_amdgcn_s_setprio(0);
        f32x16 s = s0 + s1;

        float pmax = s[0];
        #pragma unroll
        for (int jj = 1; jj < 16; ++jj) pmax = fmaxf(pmax, s[jj]);
        pmax = fmaxf(pmax, __shfl_xor(pmax, 32));
        if (!__all(pmax - m <= 8.0f)) {
            const float mnew = fmaxf(m, pmax);
            const float corr = __expf(m - mnew);
            l *= corr;
            #pragma unroll
            for (int dt = 0; dt < 4; ++dt) oacc[dt] *= corr;
            m = mnew;
        }
        float psum = 0.f;
        #pragma unroll
        for (int jj = 0; jj < 16; ++jj) {
            float pv = __expf(s[jj] - m);
            s[jj] = pv;
            psum += pv;
        }
        psum += __shfl_xor(psum, 32);
        l += psum;

        // ---- P -> fp16 B-fragments + 1-pass PV ----
        #pragma unroll
        for (int ks = 0; ks < 2; ++ks) {
            const int b0 = ks * 8;
            uint wa = cvtpkh(s[b0 + 0], s[b0 + 1]);
            uint wb = cvtpkh(s[b0 + 2], s[b0 + 3]);
            uint wc = cvtpkh(s[b0 + 4], s[b0 + 5]);
            uint wd = cvtpkh(s[b0 + 6], s[b0 + 7]);
            permswap(wa, wc); permswap(wb, wd);
            f16x8 Pf = pack4h(wa, wb, wc, wd);
            __builtin_amdgcn_s_setprio(1);
            #pragma unroll
            for (int dt = 0; dt < 4; ++dt) {
                const int row = dt * 32 + ln31;
                const int byt = row * 64 + ((ks * 32 + hi * 16) ^ ((row & 3) << 4));
                f16x8 vh = *reinterpret_cast<const f16x8*>(Vf + byt);
                oacc[dt] = __builtin_amdgcn_mfma_f32_32x32x16_f16(vh, Pf, oacc[dt], 0, 0, 0);
            }
            __builtin_amdgcn_s_setprio(0);
        }
    }

    // ---- epilogue: O -> fp16, packed layout for gemm_out8 ----
    const float invl = 1.0f / l;
    const int p   = q >> 7;
    const int rr_ = q & 127;
    const int rsw = (rr_ >> 1) & 3;
    #pragma unroll
    for (int dt = 0; dt < 4; ++dt) {
        const int kb = h * 4 + dt;
        uint16_t* bh = aoh + ((size_t)p * 128 + kb) * 4096;
        #pragma unroll
        for (int g4 = 0; g4 < 4; ++g4) {
            f16x4 hv;
            #pragma unroll
            for (int e = 0; e < 4; ++e)
                hv[e] = (f16_t)(oacc[dt][g4 * 4 + e] * invl);
            const int pos = rr_ * 32 + ((g4 ^ rsw) << 3) + 4 * hi;
            *reinterpret_cast<f16x4*>(&bh[pos]) = hv;
        }
    }
}

extern "C" void kernel_launch(void* const* d_in, const int* in_sizes, int n_in,
                              void* d_out, int out_size, void* d_ws, size_t ws_size,
                              hipStream_t stream)
{
    const float* x  = (const float*)d_in[0];
    const float* wq = (const float*)d_in[1];
    const float* wk = (const float*)d_in[2];
    const float* wv = (const float*)d_in[3];
    const float* wo = (const float*)d_in[4];
    float* out = (float*)d_out;

    float* ws = (float*)d_ws;
    float*    xq   = ws;                           // [0, 8388608)
    uint16_t* kvg  = (uint16_t*)(ws + 8388608);    // fp16 K/V tiles (8.4 MB)
    float*    xk   = ws + 12582912;
    float*    xv   = ws + 14680064;
    uint16_t* aoh  = (uint16_t*)(ws + 12582912);   // reuses xk slot after conv_kv
    uint16_t* xh   = (uint16_t*)(ws + 20971520);   // fp16 packed x
    uint16_t* wqkv = (uint16_t*)(ws + 29360128);   // fp16 packed wq|wk|wv
    uint16_t* woh  = (uint16_t*)(ws + 41943040);   // fp16 packed wo

    dim3 blk(256);
    repack_x16   <<<dim3(128, 16), blk, 0, stream>>>(x, xh);
    repack_w96_16<<<dim3(128, 64), blk, 0, stream>>>(wq, wk, wv, wqkv);
    gemm_qkv8    <<<dim3(256), dim3(512), 0, stream>>>(xh, wqkv, xq, xk, xv);
    repack_h16   <<<dim3(128, 32), blk, 0, stream>>>(wo, woh);
    rope_k       <<<dim3(20480), blk, 0, stream>>>(xq, xk);
    conv_kv      <<<dim3(64, 8), blk, 0, stream>>>(xk, xv, kvg);
    attn_mfma    <<<dim3(256), dim3(512), 0, stream>>>(xq, kvg, aoh);
    gemm_out8    <<<dim3(256), dim3(512), 0, stream>>>(aoh, woh, out);
}